// Round 8
// baseline (790.370 us; speedup 1.0000x reference)
//
#include <hip/hip_runtime.h>
#include <math.h>

// SimplePlayerModel on MI355X — Round 20.
// R19 data: qkv 84us @ MfmaUtil 19 / VALU 12 / HBM 20 / occ 39 — nothing
// saturated. Whole budget = ~9 latency-bound GEMM passes, each 4-5x its
// ~15us floor. Intra-kernel restructuring (R14-R18) never moved it; the
// cost is per-pass overhead (A re-stream + launch + scalar p stores).
// R20: chain row-local stages inside one kernel. After each stage's LN
// epilogue, transpose acc -> next-stage A-register fragments via a
// wave-local LDS bounce (no barriers), then run the next K-loop with A
// from registers. Residuals via thread-local ph/pl round-trip (L2-hot,
// keeps VGPR ~200). Pipeline: K1(emb+post+qkv0) -> attn -> K2(out0+qkv1)
// -> attn -> K3(out1+player0+player1+team). 14 -> 10 launches.

typedef __bf16 bf16x8 __attribute__((ext_vector_type(8)));
typedef __bf16 bf16x4 __attribute__((ext_vector_type(4)));
typedef __bf16 bf16x2 __attribute__((ext_vector_type(2)));
typedef float  f32x4  __attribute__((ext_vector_type(4)));
typedef unsigned short u16;
typedef unsigned short u16x8 __attribute__((ext_vector_type(8)));

__device__ __forceinline__ u16 f2b(float f) {            // fp32 -> bf16 RNE
    unsigned int u = __builtin_bit_cast(unsigned int, f);
    return (u16)((u + 0x7fffu + ((u >> 16) & 1u)) >> 16);
}
__device__ __forceinline__ float b2f(u16 u) {
    unsigned int v = ((unsigned int)u) << 16;
    return __builtin_bit_cast(float, v);
}
__device__ __forceinline__ bf16x8 ld2x64(const u16* p) { // two 8B LDS loads
    bf16x4 lo = *(const bf16x4*)p;
    bf16x4 hi = *(const bf16x4*)(p + 4);
    return __builtin_shufflevector(lo, hi, 0, 1, 2, 3, 4, 5, 6, 7);
}
__device__ __forceinline__ bf16x8 ld4x32(const u16* p) { // four 4B LDS loads
    bf16x2 a = *(const bf16x2*)p,     b = *(const bf16x2*)(p + 2);
    bf16x2 c = *(const bf16x2*)(p + 4), d = *(const bf16x2*)(p + 6);
    bf16x4 lo = __builtin_shufflevector(a, b, 0, 1, 2, 3);
    bf16x4 hi = __builtin_shufflevector(c, d, 0, 1, 2, 3);
    return __builtin_shufflevector(lo, hi, 0, 1, 2, 3, 4, 5, 6, 7);
}
__device__ __forceinline__ void split8(const float* __restrict__ s,
                                       bf16x8& hi, bf16x8& lo) {
    u16x8 h, l;
    #pragma unroll
    for (int j = 0; j < 8; ++j) {
        float v  = s[j];
        u16  hb  = f2b(v);
        h[j] = hb;
        l[j] = f2b(v - b2f(hb));
    }
    hi = __builtin_bit_cast(bf16x8, h);
    lo = __builtin_bit_cast(bf16x8, l);
}

#define MFMA __builtin_amdgcn_mfma_f32_16x16x32_bf16

// ==================== fused chain machinery (64 rows/block, 256 cols) ====

struct WCtx { const u16* sbase[8]; int sdst[8]; };

__device__ __forceinline__ void wctx_init(WCtx& c, const u16* Whi,
                                          const u16* Wlo, int tid) {
    #pragma unroll
    for (int i = 0; i < 8; ++i) {
        int cid = tid + i * 256;
        int plane = cid >> 10, nt = (cid >> 6) & 15, slot = cid & 63;
        int q = slot >> 4, cc = slot & 15;
        c.sbase[i] = (plane ? Wlo : Whi) + (long)(nt * 16 + cc) * 256 + q * 8;
        c.sdst[i]  = (plane * 16 + nt) * 512 + slot * 8;
    }
}

// stage with A in registers (Ah/Al per kt), W double-buffered in Wb.
__device__ __forceinline__ void stage256_reg(
    const bf16x8 Ah[8], const bf16x8 Al[8],
    const u16* __restrict__ Whi, const u16* __restrict__ Wlo,
    u16* __restrict__ Wb, int tid, int lane, f32x4 acc[16])
{
    WCtx c; wctx_init(c, Whi, Wlo, tid);
    u16x8 wreg[8];
    auto issueW = [&](int kt) {
        #pragma unroll
        for (int i = 0; i < 8; ++i) wreg[i] = *(const u16x8*)(c.sbase[i] + kt * 32);
    };
    auto commitW = [&](int buf) {
        #pragma unroll
        for (int i = 0; i < 8; ++i)
            *(u16x8*)&Wb[buf * 16384 + c.sdst[i]] = wreg[i];
    };
    #pragma unroll
    for (int nt = 0; nt < 16; ++nt) acc[nt] = f32x4{0.f, 0.f, 0.f, 0.f};
    __syncthreads();              // all waves done with prior Wb contents
    issueW(0); commitW(0); issueW(1);
    __syncthreads();
    #pragma unroll
    for (int kt = 0; kt < 8; ++kt) {
        const u16* wb = Wb + (kt & 1) * 16384;
        #pragma unroll
        for (int nt = 0; nt < 16; ++nt) {
            bf16x8 bhi = *(const bf16x8*)&wb[nt * 512 + lane * 8];
            bf16x8 blo = *(const bf16x8*)&wb[(16 + nt) * 512 + lane * 8];
            acc[nt] = MFMA(Al[kt], bhi, acc[nt], 0, 0, 0);
            acc[nt] = MFMA(Ah[kt], blo, acc[nt], 0, 0, 0);
            acc[nt] = MFMA(Ah[kt], bhi, acc[nt], 0, 0, 0);
        }
        if (kt + 1 < 8) {
            commitW((kt + 1) & 1);
            if (kt + 2 < 8) issueW(kt + 2);
            __syncthreads();
        }
    }
}

// stage with A streamed from global hi/lo planes (row-major, ld 256).
__device__ __forceinline__ void stage256_gA(
    const u16* __restrict__ Xa, const u16* __restrict__ Xb,
    const u16* __restrict__ Whi, const u16* __restrict__ Wlo,
    u16* __restrict__ Wb, int tid, int wv, int lane, int quad, int l16,
    f32x4 acc[16])
{
    WCtx c; wctx_init(c, Whi, Wlo, tid);
    const long arow = (long)blockIdx.x * 64 + wv * 16 + l16;
    u16x8 wreg[8];
    auto issueW = [&](int kt) {
        #pragma unroll
        for (int i = 0; i < 8; ++i) wreg[i] = *(const u16x8*)(c.sbase[i] + kt * 32);
    };
    auto commitW = [&](int buf) {
        #pragma unroll
        for (int i = 0; i < 8; ++i)
            *(u16x8*)&Wb[buf * 16384 + c.sdst[i]] = wreg[i];
    };
    bf16x8 ah[3], al[3];
    auto loadA = [&](int kt) {
        int s = kt % 3;
        long aofs = arow * 256 + kt * 32 + quad * 8;
        ah[s] = *(const bf16x8*)&Xa[aofs];
        al[s] = *(const bf16x8*)&Xb[aofs];
    };
    #pragma unroll
    for (int nt = 0; nt < 16; ++nt) acc[nt] = f32x4{0.f, 0.f, 0.f, 0.f};
    issueW(0); commitW(0); issueW(1);
    loadA(0); loadA(1);
    __syncthreads();
    #pragma unroll
    for (int kt = 0; kt < 8; ++kt) {
        if (kt + 2 < 8) loadA(kt + 2);
        const u16* wb = Wb + (kt & 1) * 16384;
        const int s = kt % 3;
        #pragma unroll
        for (int nt = 0; nt < 16; ++nt) {
            bf16x8 bhi = *(const bf16x8*)&wb[nt * 512 + lane * 8];
            bf16x8 blo = *(const bf16x8*)&wb[(16 + nt) * 512 + lane * 8];
            acc[nt] = MFMA(al[s], bhi, acc[nt], 0, 0, 0);
            acc[nt] = MFMA(ah[s], blo, acc[nt], 0, 0, 0);
            acc[nt] = MFMA(ah[s], bhi, acc[nt], 0, 0, 0);
        }
        if (kt + 1 < 8) {
            commitW((kt + 1) & 1);
            if (kt + 2 < 8) issueW(kt + 2);
            __syncthreads();
        }
    }
}

// acc -> next-stage A fragments, wave-local LDS bounce (16 rows/wave).
// Xw stride 264 u16 (16B-mult, ~2-way banks). hi round then lo round.
__device__ __forceinline__ void xpose(const f32x4 acc[16], u16* __restrict__ Wb,
                                      int wv, int quad, int l16,
                                      bf16x8 Ah[8], bf16x8 Al[8])
{
    u16* Xw = Wb + wv * (16 * 264);
    __syncthreads();                     // all waves done reading Wb
    #pragma unroll
    for (int nt = 0; nt < 16; ++nt)
        #pragma unroll
        for (int r = 0; r < 4; ++r)
            Xw[(quad * 4 + r) * 264 + nt * 16 + l16] = f2b(acc[nt][r]);
    #pragma unroll
    for (int kt = 0; kt < 8; ++kt)
        Ah[kt] = *(const bf16x8*)&Xw[l16 * 264 + kt * 32 + quad * 8];
    #pragma unroll
    for (int nt = 0; nt < 16; ++nt)
        #pragma unroll
        for (int r = 0; r < 4; ++r) {
            float v = acc[nt][r];
            u16 hb = f2b(v);
            Xw[(quad * 4 + r) * 264 + nt * 16 + l16] = f2b(v - b2f(hb));
        }
    #pragma unroll
    for (int kt = 0; kt < 8; ++kt)
        Al[kt] = *(const bf16x8*)&Xw[l16 * 264 + kt * 32 + quad * 8];
    // next stage's entry barrier protects Xw before W staging overwrites it
}

__device__ __forceinline__ void ln_stats(const f32x4 acc[16],
                                         float mean[4], float rstd[4])
{
    float s1[4] = {0, 0, 0, 0}, s2[4] = {0, 0, 0, 0};
    #pragma unroll
    for (int nt = 0; nt < 16; ++nt)
        #pragma unroll
        for (int r = 0; r < 4; ++r) {
            s1[r] += acc[nt][r];
            s2[r] += acc[nt][r] * acc[nt][r];
        }
    #pragma unroll
    for (int off = 1; off < 16; off <<= 1)
        #pragma unroll
        for (int r = 0; r < 4; ++r) {
            s1[r] += __shfl_xor(s1[r], off, 64);
            s2[r] += __shfl_xor(s2[r], off, 64);
        }
    #pragma unroll
    for (int r = 0; r < 4; ++r) {
        mean[r] = s1[r] * (1.0f / 256.f);
        float var = s2[r] * (1.0f / 256.f) - mean[r] * mean[r];
        rstd[r] = rsqrtf(var + 1e-5f);
    }
}

// bias + LN (+res from ph/pl, same-thread addresses) + store ph/pl;
// acc updated in place to the final p values.
template<bool RES>
__device__ __forceinline__ void epi_ln_store(f32x4 acc[16],
    const float* __restrict__ bias, const float* __restrict__ g,
    const float* __restrict__ beta, u16* __restrict__ ph, u16* __restrict__ pl,
    int wv, int quad, int l16)
{
    #pragma unroll
    for (int nt = 0; nt < 16; ++nt) {
        float bc = bias[nt * 16 + l16];
        #pragma unroll
        for (int r = 0; r < 4; ++r) acc[nt][r] += bc;
    }
    float mean[4], rstd[4];
    ln_stats(acc, mean, rstd);
    #pragma unroll
    for (int nt = 0; nt < 16; ++nt) {
        int col = nt * 16 + l16;
        float gc = g[col], bc2 = beta[col];
        #pragma unroll
        for (int r = 0; r < 4; ++r) {
            long row = (long)blockIdx.x * 64 + wv * 16 + quad * 4 + r;
            float v = (acc[nt][r] - mean[r]) * rstd[r] * gc + bc2;
            if constexpr (RES)
                v += b2f(ph[row * 256 + col]) + b2f(pl[row * 256 + col]);
            acc[nt][r] = v;
            u16 hb = f2b(v);
            ph[row * 256 + col] = hb;
            pl[row * 256 + col] = f2b(v - b2f(hb));
        }
    }
}

// qkv panel epilogue: bias, scatter to attention layout [n][h][s][d].
__device__ __forceinline__ void epi_qkv(const f32x4 acc[16],
    const float* __restrict__ bias, u16* __restrict__ Y,
    int wv, int quad, int l16)
{
    #pragma unroll
    for (int nt = 0; nt < 16; ++nt) {
        int col = nt * 16 + l16;
        float bc = bias[col];
        #pragma unroll
        for (int r = 0; r < 4; ++r) {
            long row = (long)blockIdx.x * 64 + wv * 16 + quad * 4 + r;
            float v = acc[nt][r] + bc;
            long idx = ((long)((row & 63) * 4 + (col >> 6)) * 512
                        + (row >> 6)) * 64 + (col & 63);
            Y[idx] = f2b(v);
        }
    }
}

// ===================== K1: emb + post + qkv(L0) ==========================
__global__ __launch_bounds__(256)
void fused_k1(const float* __restrict__ x,
              const u16* __restrict__ emb_wp, const float* __restrict__ emb_b,
              const float* __restrict__ emb_g, const float* __restrict__ emb_bt,
              const u16* __restrict__ post_wp, const float* __restrict__ post_b,
              const float* __restrict__ post_g, const float* __restrict__ post_bt,
              const u16* __restrict__ cwb, const float* __restrict__ cbf,
              u16* __restrict__ ph, u16* __restrict__ pl,
              u16* __restrict__ qb, u16* __restrict__ kb, u16* __restrict__ vh)
{
    __shared__ u16 Wb[32768];
    const int tid = threadIdx.x;
    const int wv = tid >> 6, lane = tid & 63;
    const int quad = lane >> 4, l16 = lane & 15;

    f32x4 acc[16];
    // ---- S1: emb (IN=64, KT=2), whole W preloaded (exactly 64KB)
    {
        #pragma unroll
        for (int i = 0; i < 16; ++i) {
            int cid = tid + i * 256;                 // 0..4095
            int kt = cid >> 11;
            int c2 = cid & 2047;
            int plane = c2 >> 10, nt = (c2 >> 6) & 15, slot = c2 & 63;
            int q = slot >> 4, cc = slot & 15;
            const u16* src = emb_wp + plane * 16384
                           + (long)(nt * 16 + cc) * 64 + kt * 32 + q * 8;
            *(u16x8*)&Wb[kt * 16384 + (plane * 16 + nt) * 512 + slot * 8] =
                *(const u16x8*)src;
        }
        bf16x8 eh[2], el[2];
        #pragma unroll
        for (int kt = 0; kt < 2; ++kt) {
            float av[8];
            long aofs = ((long)blockIdx.x * 64 + wv * 16 + l16) * 64
                      + kt * 32 + quad * 8;
            *(f32x4*)&av[0] = *(const f32x4*)&x[aofs];
            *(f32x4*)&av[4] = *(const f32x4*)&x[aofs + 4];
            split8(av, eh[kt], el[kt]);
        }
        #pragma unroll
        for (int nt = 0; nt < 16; ++nt) acc[nt] = f32x4{0.f, 0.f, 0.f, 0.f};
        __syncthreads();
        #pragma unroll
        for (int kt = 0; kt < 2; ++kt) {
            const u16* wb = Wb + kt * 16384;
            #pragma unroll
            for (int nt = 0; nt < 16; ++nt) {
                bf16x8 bhi = *(const bf16x8*)&wb[nt * 512 + lane * 8];
                bf16x8 blo = *(const bf16x8*)&wb[(16 + nt) * 512 + lane * 8];
                acc[nt] = MFMA(el[kt], bhi, acc[nt], 0, 0, 0);
                acc[nt] = MFMA(eh[kt], blo, acc[nt], 0, 0, 0);
                acc[nt] = MFMA(eh[kt], bhi, acc[nt], 0, 0, 0);
            }
        }
    }
    epi_ln_store<false>(acc, emb_b, emb_g, emb_bt, ph, pl, wv, quad, l16);

    // ---- S2: post (res = emb-out in ph/pl, thread-local)
    bf16x8 Ah[8], Al[8];
    xpose(acc, Wb, wv, quad, l16, Ah, Al);
    stage256_reg(Ah, Al, post_wp, post_wp + 65536, Wb, tid, lane, acc);
    epi_ln_store<true>(acc, post_b, post_g, post_bt, ph, pl, wv, quad, l16);

    // ---- S3: qkv(L0), 3 panels
    xpose(acc, Wb, wv, quad, l16, Ah, Al);
    u16* Ys[3] = {qb, kb, vh};
    #pragma unroll 1
    for (int wsel = 0; wsel < 3; ++wsel) {
        const u16* whi = cwb + (long)wsel * 65536;
        const u16* wlo = cwb + 393216 + (long)wsel * 65536;
        stage256_reg(Ah, Al, whi, wlo, Wb, tid, lane, acc);
        epi_qkv(acc, cbf + wsel * 256, Ys[wsel], wv, quad, l16);
    }
}

// ===================== K2: out(L0)+LN+res + qkv(L1) ======================
__global__ __launch_bounds__(256)
void fused_k2(const u16* __restrict__ ofh, const u16* __restrict__ ofl,
              const u16* __restrict__ outw_hi, const u16* __restrict__ outw_lo,
              const float* __restrict__ outb, const float* __restrict__ og,
              const float* __restrict__ obt,
              const u16* __restrict__ cwL, const float* __restrict__ cbL,
              u16* __restrict__ ph, u16* __restrict__ pl,
              u16* __restrict__ qb, u16* __restrict__ kb, u16* __restrict__ vh)
{
    __shared__ u16 Wb[32768];
    const int tid = threadIdx.x;
    const int wv = tid >> 6, lane = tid & 63;
    const int quad = lane >> 4, l16 = lane & 15;

    f32x4 acc[16];
    stage256_gA(ofh, ofl, outw_hi, outw_lo, Wb, tid, wv, lane, quad, l16, acc);
    epi_ln_store<true>(acc, outb, og, obt, ph, pl, wv, quad, l16);

    bf16x8 Ah[8], Al[8];
    xpose(acc, Wb, wv, quad, l16, Ah, Al);
    u16* Ys[3] = {qb, kb, vh};
    #pragma unroll 1
    for (int wsel = 0; wsel < 3; ++wsel) {
        const u16* whi = cwL + (long)wsel * 65536;
        const u16* wlo = cwL + 393216 + (long)wsel * 65536;
        stage256_reg(Ah, Al, whi, wlo, Wb, tid, lane, acc);
        epi_qkv(acc, cbL + wsel * 256, Ys[wsel], wv, quad, l16);
    }
}

// ============ K3: out(L1)+LN+res + player0 + player1 + team-reduce =======
__global__ __launch_bounds__(256)
void fused_k3(const u16* __restrict__ ofh, const u16* __restrict__ ofl,
              const u16* __restrict__ outw_hi, const u16* __restrict__ outw_lo,
              const float* __restrict__ outb, const float* __restrict__ og,
              const float* __restrict__ obt,
              const u16* __restrict__ player_wp, const float* __restrict__ player_b,
              const float* __restrict__ player_g, const float* __restrict__ player_bt,
              const float* __restrict__ xmask, float* __restrict__ teams,
              u16* __restrict__ ph, u16* __restrict__ pl)
{
    __shared__ u16 Wb[32768];
    const int tid = threadIdx.x;
    const int wv = tid >> 6, lane = tid & 63;
    const int quad = lane >> 4, l16 = lane & 15;

    f32x4 acc[16];
    // S1: out-proj L1
    stage256_gA(ofh, ofl, outw_hi, outw_lo, Wb, tid, wv, lane, quad, l16, acc);
    epi_ln_store<true>(acc, outb, og, obt, ph, pl, wv, quad, l16);

    // S2: player0
    bf16x8 Ah[8], Al[8];
    xpose(acc, Wb, wv, quad, l16, Ah, Al);
    stage256_reg(Ah, Al, player_wp, player_wp + 131072, Wb, tid, lane, acc);
    epi_ln_store<true>(acc, player_b, player_g, player_bt, ph, pl, wv, quad, l16);

    // S3: player1 + TEAM epilogue
    xpose(acc, Wb, wv, quad, l16, Ah, Al);
    stage256_reg(Ah, Al, player_wp + 65536, player_wp + 131072 + 65536,
                 Wb, tid, lane, acc);
    {
        const float* bias = player_b + 256;
        const float* g    = player_g + 256;
        const float* beta = player_bt + 256;
        #pragma unroll
        for (int nt = 0; nt < 16; ++nt) {
            float bc = bias[nt * 16 + l16];
            #pragma unroll
            for (int r = 0; r < 4; ++r) acc[nt][r] += bc;
        }
        float mean[4], rstd[4];
        ln_stats(acc, mean, rstd);
        float m[4];
        #pragma unroll
        for (int r = 0; r < 4; ++r) {
            long row = (long)blockIdx.x * 64 + wv * 16 + quad * 4 + r;
            m[r] = (xmask[row * 64 + 63] == 1.0f) ? 1.0f : 0.0f;
        }
        float ts[16];
        #pragma unroll
        for (int nt = 0; nt < 16; ++nt) {
            int col = nt * 16 + l16;
            float gc = g[col], bc2 = beta[col];
            ts[nt] = 0.f;
            #pragma unroll
            for (int r = 0; r < 4; ++r) {
                long row = (long)blockIdx.x * 64 + wv * 16 + quad * 4 + r;
                float v = (acc[nt][r] - mean[r]) * rstd[r] * gc + bc2;
                v += b2f(ph[row * 256 + col]) + b2f(pl[row * 256 + col]);
                ts[nt] += m[r] * v;
            }
        }
        #pragma unroll
        for (int nt = 0; nt < 16; ++nt) {
            ts[nt] += __shfl_xor(ts[nt], 16, 64);
            ts[nt] += __shfl_xor(ts[nt], 32, 64);
        }
        __syncthreads();                       // all Wb reads done
        float* tsum = (float*)Wb;              // alias: 4 x 256 floats
        if (quad == 0) {
            #pragma unroll
            for (int nt = 0; nt < 16; ++nt)
                tsum[wv * 256 + nt * 16 + l16] = ts[nt];
        }
        __syncthreads();
        if (tid < 256) {
            float tot = tsum[tid] + tsum[256 + tid]
                      + tsum[512 + tid] + tsum[768 + tid];
            teams[(long)blockIdx.x * 512 + tid]       = tot;
            teams[(long)blockIdx.x * 512 + 256 + tid] = tot;
        }
    }
}

// ----------------------------------------------- combined in_proj @ qkv_proj
__global__ __launch_bounds__(256)
void combine_kernel(const float* __restrict__ inw, const float* __restrict__ inb,
                    const float* __restrict__ qw, const float* __restrict__ kw,
                    const float* __restrict__ vw, const float* __restrict__ qb,
                    const float* __restrict__ kb, const float* __restrict__ vb,
                    u16* __restrict__ cw, float* __restrict__ cb)
{
    int idx = blockIdx.y, L = idx / 3, wsel = idx % 3;
    const float* Wa = inw + (long)L * 768 * 256 + wsel * 65536;
    const float* ba = inb + L * 768 + wsel * 256;
    const float* Wf = (wsel == 0 ? qw : wsel == 1 ? kw : vw) + (long)L * 65536;
    const float* bf = (wsel == 0 ? qb : wsel == 1 ? kb : vb) + L * 256;

    int o = blockIdx.x, j = threadIdx.x;
    float s = 0.f;
    for (int mm = 0; mm < 256; ++mm)
        s += Wa[o * 256 + mm] * Wf[mm * 256 + j];
    u16 hb = f2b(s);
    cw[(long)idx * 65536 + o * 256 + j] = hb;
    cw[393216 + (long)idx * 65536 + o * 256 + j] = f2b(s - b2f(hb));

    __shared__ float red[256];
    red[j] = Wa[o * 256 + j] * bf[j];
    __syncthreads();
    for (int st = 128; st > 0; st >>= 1) {
        if (j < st) red[j] += red[j + st];
        __syncthreads();
    }
    if (j == 0) cb[idx * 256 + o] = red[0] + ba[o];
}

// ------------------------------------------- fp32 -> hi/lo bf16 weight planes
__global__ __launch_bounds__(256)
void cast_split_multi(const float* s0, u16* d0, int n0,
                      const float* s1, u16* d1, int n1,
                      const float* s2, u16* d2, int n2,
                      const float* s3, u16* d3, int n3,
                      const float* s4, u16* d4, int n4,
                      const float* s5, u16* d5, int n5)
{
    const float* s; u16* d; int n;
    switch (blockIdx.y) {
        case 0: s = s0; d = d0; n = n0; break;
        case 1: s = s1; d = d1; n = n1; break;
        case 2: s = s2; d = d2; n = n2; break;
        case 3: s = s3; d = d3; n = n3; break;
        case 4: s = s4; d = d4; n = n4; break;
        default: s = s5; d = d5; n = n5; break;
    }
    int i = (blockIdx.x * 256 + threadIdx.x) * 4;
    if (i >= n) return;
    float4 v = *(const float4*)&s[i];
    ushort4 h, l;
    h.x = f2b(v.x); l.x = f2b(v.x - b2f(h.x));
    h.y = f2b(v.y); l.y = f2b(v.y - b2f(h.y));
    h.z = f2b(v.z); l.z = f2b(v.z - b2f(h.z));
    h.w = f2b(v.w); l.w = f2b(v.w - b2f(h.w));
    *(ushort4*)&d[i] = h;
    *(ushort4*)&d[n + i] = l;
}

// ------------------------------------------------------- MFMA flash attention
// R13 version (82.7us): inputs in [n][h][s][d]; V staged via LDS transpose,
// 2 barriers/tile; K fragments direct from global. Grid (64,4,4).
#define VTS 66
#define PS  68
#define EXP2SCALE 0.18033688089184986f   // 0.125 * log2(e)

__global__ __launch_bounds__(256)
void attn_kernel(const u16* __restrict__ qbuf, const u16* __restrict__ kbuf,
                 const u16* __restrict__ vh,
                 u16* __restrict__ ofh, u16* __restrict__ ofl)
{
    const int n = blockIdx.x, h = blockIdx.y, sq = blockIdx.z;
    const int tid = threadIdx.x;
    const int wv = tid >> 6, lane = tid & 63;
    const int quad = lane >> 4, l16 = lane & 15;
    const long nhb = (long)(n * 4 + h) * 32768;   // (n,h) panel base, 512x64

    __shared__ u16 Vth[64 * VTS];
    __shared__ u16 Pbh[4][32 * PS];

    bf16x8 qf[2][2];
    #pragma unroll
    for (int rt = 0; rt < 2; ++rt)
        #pragma unroll
        for (int kc = 0; kc < 2; ++kc) {
            long s = sq * 128 + wv * 32 + rt * 16 + l16;
            qf[rt][kc] = *(const bf16x8*)&qbuf[nhb + s * 64 + kc * 32 + quad * 8];
        }

    f32x4 o[2][4];
    #pragma unroll
    for (int rt = 0; rt < 2; ++rt)
        #pragma unroll
        for (int dt = 0; dt < 4; ++dt) o[rt][dt] = f32x4{0.f, 0.f, 0.f, 0.f};
    float l_run[2][4] = {{0.f, 0.f, 0.f, 0.f}, {0.f, 0.f, 0.f, 0.f}};

    for (int tb = 0; tb < 8; ++tb) {
        __syncthreads();
        // V tile stage: fully coalesced contiguous read, transpose to LDS
        for (int i = tid; i < 512; i += 256) {
            int t = i >> 3, c = i & 7;
            u16x8 hvv = *(const u16x8*)&vh[nhb + (long)(tb * 64 + t) * 64 + c * 8];
            #pragma unroll
            for (int j = 0; j < 8; ++j)
                Vth[(c * 8 + j) * VTS + t] = hvv[j];
        }
        __syncthreads();

        f32x4 sA[2][4];
        #pragma unroll
        for (int rt = 0; rt < 2; ++rt)
            #pragma unroll
            for (int tt = 0; tt < 4; ++tt) sA[rt][tt] = f32x4{0.f, 0.f, 0.f, 0.f};
        #pragma unroll
        for (int kc = 0; kc < 2; ++kc)
            #pragma unroll
            for (int tt = 0; tt < 4; ++tt) {
                bf16x8 kf = *(const bf16x8*)
                    &kbuf[nhb + (long)(tb * 64 + tt * 16 + l16) * 64
                          + kc * 32 + quad * 8];
                sA[0][tt] = MFMA(qf[0][kc], kf, sA[0][tt], 0, 0, 0);
                sA[1][tt] = MFMA(qf[1][kc], kf, sA[1][tt], 0, 0, 0);
            }

        #pragma unroll
        for (int rt = 0; rt < 2; ++rt)
            #pragma unroll
            for (int r = 0; r < 4; ++r) {
                float p0 = exp2f(sA[rt][0][r] * EXP2SCALE);
                float p1 = exp2f(sA[rt][1][r] * EXP2SCALE);
                float p2 = exp2f(sA[rt][2][r] * EXP2SCALE);
                float p3 = exp2f(sA[rt][3][r] * EXP2SCALE);
                int prow = (rt * 16 + quad * 4 + r) * PS + l16;
                Pbh[wv][prow +  0] = f2b(p0);
                Pbh[wv][prow + 16] = f2b(p1);
                Pbh[wv][prow + 32] = f2b(p2);
                Pbh[wv][prow + 48] = f2b(p3);
                l_run[rt][r] += (p0 + p1) + (p2 + p3);
            }

        #pragma unroll
        for (int kc = 0; kc < 2; ++kc) {
            bf16x8 pfh[2];
            #pragma unroll
            for (int rt = 0; rt < 2; ++rt)
                pfh[rt] = ld2x64(&Pbh[wv][(rt * 16 + l16) * PS
                                          + kc * 32 + quad * 8]);
            #pragma unroll
            for (int dt = 0; dt < 4; ++dt) {
                bf16x8 vfh = ld4x32(&Vth[(dt * 16 + l16) * VTS
                                         + kc * 32 + quad * 8]);
                o[0][dt] = MFMA(pfh[0], vfh, o[0][dt], 0, 0, 0);
                o[1][dt] = MFMA(pfh[1], vfh, o[1][dt], 0, 0, 0);
            }
        }
    }

    #pragma unroll
    for (int off = 1; off < 16; off <<= 1)
        #pragma unroll
        for (int rt = 0; rt < 2; ++rt)
            #pragma unroll
            for (int r = 0; r < 4; ++r)
                l_run[rt][r] += __shfl_xor(l_run[rt][r], off, 64);

    #pragma unroll
    for (int rt = 0; rt < 2; ++rt)
        #pragma unroll
        for (int r = 0; r < 4; ++r) {
            float inv = 1.0f / l_run[rt][r];
            long s = sq * 128 + wv * 32 + rt * 16 + quad * 4 + r;
            #pragma unroll
            for (int dt = 0; dt < 4; ++dt) {
                long idx = (s * 64 + n) * 256 + h * 64 + dt * 16 + l16;
                float val = o[rt][dt][r] * inv;
                u16 hb = f2b(val);
                ofh[idx] = hb;
                ofl[idx] = f2b(val - b2f(hb));
            }
        }
}

// ---------------------------------------- tail GEMM (512-row team layers)
template<int IN, int OUT, bool RES>
__global__ __launch_bounds__(256)
void tail_gemm(const float* __restrict__ X,
               const u16* __restrict__ Whi, const u16* __restrict__ Wlo,
               const float* __restrict__ bias,
               const float* __restrict__ g, const float* __restrict__ beta,
               const float* __restrict__ res, float* __restrict__ Y)
{
    constexpr int NTW = OUT / 64;
    constexpr int KT  = IN / 32;
    const int tid = threadIdx.x;
    const int wv = tid >> 6, lane = tid & 63;
    const int quad = lane >> 4, l16 = lane & 15;
    const int row0 = blockIdx.x * 16;
    const int colbase = wv * (OUT / 4);

    f32x4 acc[NTW];
    #pragma unroll
    for (int nt = 0; nt < NTW; ++nt) acc[nt] = f32x4{0.f, 0.f, 0.f, 0.f};

    #pragma unroll
    for (int kt = 0; kt < KT; ++kt) {
        float av[8];
        long aofs = (long)(row0 + l16) * IN + kt * 32 + quad * 8;
        *(f32x4*)&av[0] = *(const f32x4*)&X[aofs];
        *(f32x4*)&av[4] = *(const f32x4*)&X[aofs + 4];
        bf16x8 ah, al;
        split8(av, ah, al);
        #pragma unroll
        for (int nt = 0; nt < NTW; ++nt) {
            long wofs = (long)(colbase + nt * 16 + l16) * IN + kt * 32 + quad * 8;
            bf16x8 bhi = *(const bf16x8*)&Whi[wofs];
            bf16x8 blo = *(const bf16x8*)&Wlo[wofs];
            acc[nt] = MFMA(al, bhi, acc[nt], 0, 0, 0);
            acc[nt] = MFMA(ah, blo, acc[nt], 0, 0, 0);
            acc[nt] = MFMA(ah, bhi, acc[nt], 0, 0, 0);
        }
    }

    #pragma unroll
    for (int nt = 0; nt < NTW; ++nt) {
        float bc = bias[colbase + nt * 16 + l16];
        #pragma unroll
        for (int r = 0; r < 4; ++r) acc[nt][r] += bc;
    }

    float s1[4] = {0, 0, 0, 0}, s2[4] = {0, 0, 0, 0};
    #pragma unroll
    for (int nt = 0; nt < NTW; ++nt)
        #pragma unroll
        for (int r = 0; r < 4; ++r) {
            s1[r] += acc[nt][r];
            s2[r] += acc[nt][r] * acc[nt][r];
        }
    #pragma unroll
    for (int off = 1; off < 16; off <<= 1)
        #pragma unroll
        for (int r = 0; r < 4; ++r) {
            s1[r] += __shfl_xor(s1[r], off, 64);
            s2[r] += __shfl_xor(s2[r], off, 64);
        }
    __shared__ float r1[64], r2[64];
    if (l16 == 0) {
        #pragma unroll
        for (int r = 0; r < 4; ++r) {
            r1[wv * 16 + quad * 4 + r] = s1[r];
            r2[wv * 16 + quad * 4 + r] = s2[r];
        }
    }
    __syncthreads();
    float mean[4], rstd[4];
    #pragma unroll
    for (int r = 0; r < 4; ++r) {
        int rr = quad * 4 + r;
        float t1 = r1[rr] + r1[16 + rr] + r1[32 + rr] + r1[48 + rr];
        float t2 = r2[rr] + r2[16 + rr] + r2[32 + rr] + r2[48 + rr];
        mean[r] = t1 * (1.0f / OUT);
        float var = t2 * (1.0f / OUT) - mean[r] * mean[r];
        rstd[r] = rsqrtf(var + 1e-5f);
    }
    #pragma unroll
    for (int nt = 0; nt < NTW; ++nt) {
        int col = colbase + nt * 16 + l16;
        float gc = g[col], bc2 = beta[col];
        #pragma unroll
        for (int r = 0; r < 4; ++r) {
            int row = row0 + quad * 4 + r;
            float v = (acc[nt][r] - mean[r]) * rstd[r] * gc + bc2;
            if constexpr (RES) v += res[(long)row * OUT + col];
            Y[(long)row * OUT + col] = v;
        }
    }
}

// --------------------- fused pre (512->256) + lnf + pred -> out[512] fp32
__global__ __launch_bounds__(256)
void tail_pred(const float* __restrict__ X,
               const u16* __restrict__ Whi, const u16* __restrict__ Wlo,
               const float* __restrict__ bias,
               const float* __restrict__ g, const float* __restrict__ beta,
               const float* __restrict__ lnf_g, const float* __restrict__ lnf_b,
               const float* __restrict__ pw, const float* __restrict__ pb,
               float* __restrict__ out)
{
    constexpr int IN = 512, OUT = 256, NTW = 4, KT = 16;
    const int tid = threadIdx.x;
    const int wv = tid >> 6, lane = tid & 63;
    const int quad = lane >> 4, l16 = lane & 15;
    const int row0 = blockIdx.x * 16;
    const int colbase = wv * 64;

    f32x4 acc[NTW];
    #pragma unroll
    for (int nt = 0; nt < NTW; ++nt) acc[nt] = f32x4{0.f, 0.f, 0.f, 0.f};

    #pragma unroll
    for (int kt = 0; kt < KT; ++kt) {
        float av[8];
        long aofs = (long)(row0 + l16) * IN + kt * 32 + quad * 8;
        *(f32x4*)&av[0] = *(const f32x4*)&X[aofs];
        *(f32x4*)&av[4] = *(const f32x4*)&X[aofs + 4];
        bf16x8 ah, al;
        split8(av, ah, al);
        #pragma unroll
        for (int nt = 0; nt < NTW; ++nt) {
            long wofs = (long)(colbase + nt * 16 + l16) * IN + kt * 32 + quad * 8;
            bf16x8 bhi = *(const bf16x8*)&Whi[wofs];
            bf16x8 blo = *(const bf16x8*)&Wlo[wofs];
            acc[nt] = MFMA(al, bhi, acc[nt], 0, 0, 0);
            acc[nt] = MFMA(ah, blo, acc[nt], 0, 0, 0);
            acc[nt] = MFMA(ah, bhi, acc[nt], 0, 0, 0);
        }
    }
    #pragma unroll
    for (int nt = 0; nt < NTW; ++nt) {
        float bc = bias[colbase + nt * 16 + l16];
        #pragma unroll
        for (int r = 0; r < 4; ++r) acc[nt][r] += bc;
    }

    __shared__ float r1[64], r2[64];
    // ---- LN 1 (pre_g/pre_beta)
    float s1[4] = {0, 0, 0, 0}, s2[4] = {0, 0, 0, 0};
    #pragma unroll
    for (int nt = 0; nt < NTW; ++nt)
        #pragma unroll
        for (int r = 0; r < 4; ++r) {
            s1[r] += acc[nt][r];
            s2[r] += acc[nt][r] * acc[nt][r];
        }
    #pragma unroll
    for (int off = 1; off < 16; off <<= 1)
        #pragma unroll
        for (int r = 0; r < 4; ++r) {
            s1[r] += __shfl_xor(s1[r], off, 64);
            s2[r] += __shfl_xor(s2[r], off, 64);
        }
    if (l16 == 0)
        #pragma unroll
        for (int r = 0; r < 4; ++r) {
            r1[wv * 16 + quad * 4 + r] = s1[r];
            r2[wv * 16 + quad * 4 + r] = s2[r];
        }
    __syncthreads();
    float vv[NTW][4];
    #pragma unroll
    for (int r = 0; r < 4; ++r) {
        int rr = quad * 4 + r;
        float t1 = r1[rr] + r1[16 + rr] + r1[32 + rr] + r1[48 + rr];
        float t2 = r2[rr] + r2[16 + rr] + r2[32 + rr] + r2[48 + rr];
        float mean = t1 * (1.0f / OUT);
        float rstd = rsqrtf(t2 * (1.0f / OUT) - mean * mean + 1e-5f);
        #pragma unroll
        for (int nt = 0; nt < NTW; ++nt) {
            int col = colbase + nt * 16 + l16;
            vv[nt][r] = (acc[nt][r] - mean) * rstd * g[col] + beta[col];
        }
    }
    // ---- LN 2 (lnf)
    float u1[4] = {0, 0, 0, 0}, u2[4] = {0, 0, 0, 0};
    #pragma unroll
    for (int nt = 0; nt < NTW; ++nt)
        #pragma unroll
        for (int r = 0; r < 4; ++r) {
            u1[r] += vv[nt][r];
            u2[r] += vv[nt][r] * vv[nt][r];
        }
    #pragma unroll
    for (int off = 1; off < 16; off <<= 1)
        #pragma unroll
        for (int r = 0; r < 4; ++r) {
            u1[r] += __shfl_xor(u1[r], off, 64);
            u2[r] += __shfl_xor(u2[r], off, 64);
        }
    __syncthreads();
    if (l16 == 0)
        #pragma unroll
        for (int r = 0; r < 4; ++r) {
            r1[wv * 16 + quad * 4 + r] = u1[r];
            r2[wv * 16 + quad * 4 + r] = u2[r];
        }
    __syncthreads();
    // ---- pred dot
    float pd[4];
    #pragma unroll
    for (int r = 0; r < 4; ++r) {
        int rr = quad * 4 + r;
        float t1 = r1[rr] + r1[16 + rr] + r1[32 + rr] + r1[48 + rr];
        float t2 = r2[rr] + r2[16 + rr] + r2[32 + rr] + r2[48 + rr];
        float mean = t1 * (1.0f / OUT);
        float rstd = rsqrtf(t2 * (1.0f / OUT) - mean * mean + 1e-5f);
        pd[r] = 0.f;
        #pragma unroll
        for (int nt = 0; nt < NTW; ++nt) {
            int col = colbase + nt * 16 + l16;
            float v2 = (vv[nt][r] - mean) * rstd * lnf_g[col] + lnf_b[col];
            pd[r] += v2 * pw[col];
        }
    }
    #pragma unroll
    for (int off = 1; off < 16; off <<= 1)
        #pragma unroll
        for (int r = 0; r < 4; ++r)
            pd[r] += __shfl_xor(pd[r], off, 64);
    __syncthreads();
    if (l16 == 0)
        #pragma unroll
        for (int r = 0; r < 4; ++r)
            r1[wv * 16 + quad * 4 + r] = pd[r];
    __syncthreads();
    if (wv == 0 && l16 == 0) {
        #pragma unroll
        for (int r = 0; r < 4; ++r) {
            int rr = quad * 4 + r;
            out[row0 + rr] = r1[rr] + r1[16 + rr] + r1[32 + rr] + r1[48 + rr]
                           + pb[0];
        }
    }
}

// =========================================================================
extern "C" void kernel_launch(void* const* d_in, const int* in_sizes, int n_in,
                              void* d_out, int out_size, void* d_ws, size_t ws_size,
                              hipStream_t stream)
{
    const float* x         = (const float*)d_in[0];
    const float* emb_w     = (const float*)d_in[1];
    const float* emb_b     = (const float*)d_in[2];
    const float* emb_g     = (const float*)d_in[3];
    const float* emb_beta  = (const float*)d_in[4];
    const float* post_w    = (const float*)d_in[5];
    const float* post_b    = (const float*)d_in[6];
    const float* post_g    = (const float*)d_in[7];
    const float* post_beta = (const float*)d_in[8];
    const float* attn_qw   = (const float*)d_in[9];
    const float* attn_qb   = (const float*)d_in[10];
    const float* attn_kw   = (const float*)d_in[11];
    const float* attn_kb   = (const float*)d_in[12];
    const float* attn_vw   = (const float*)d_in[13];
    const float* attn_vb   = (const float*)d_in[14];
    const float* attn_inw  = (const float*)d_in[15];
    const float* attn_inb  = (const float*)d_in[16];
    const float* attn_outw = (const float*)d_in[17];
    const float* attn_outb = (const float*)d_in[18];
    const float* attn_g    = (const float*)d_in[19];
    const float* attn_beta = (const float*)d_in[20];
    const float* player_w  = (const float*)d_in[21];
    const float* player_b  = (const float*)d_in[22];
    const float* player_g  = (const float*)d_in[23];
    const float* player_bt = (const float*)d_in[24];
    const float* team_w    = (const float*)d_in[25];
    const float* team_b    = (const float*)d_in[26];
    const float* team_g    = (const float*)d_in[27];
    const float* team_beta = (const float*)d_in[28];
    const float* pre_w     = (const float*)d_in[29];
    const float* pre_b     = (const float*)d_in[30];
    const float* pre_g     = (const float*)d_in[31];
    const float* pre_beta  = (const float*)d_in[32];
    const float* lnf_g     = (const float*)d_in[33];
    const float* lnf_b     = (const float*)d_in[34];
    const float* pred_w    = (const float*)d_in[35];
    const float* pred_b    = (const float*)d_in[36];

    // ---- workspace layout
    char* base = (char*)d_ws;
    const size_t NR = (size_t)32768 * 256;
    u16* ph  = (u16*)base;  base += NR * 2;
    u16* pl  = (u16*)base;  base += NR * 2;
    u16* ofh = (u16*)base;  base += NR * 2;
    u16* ofl = (u16*)base;  base += NR * 2;
    u16* vh  = (u16*)base;  base += NR * 2;
    u16* qb  = (u16*)base;  base += NR * 2;
    u16* kb  = (u16*)base;  base += NR * 2;
    float* teams0 = (float*)base; base += (size_t)512 * 512 * 4;
    float* teams1 = (float*)base; base += (size_t)512 * 512 * 4;
    u16* emb_wp    = (u16*)base;  base += (size_t)2 * 16384 * 2;
    u16* post_wp   = (u16*)base;  base += (size_t)2 * 65536 * 2;
    u16* outw_p    = (u16*)base;  base += (size_t)2 * 131072 * 2;
    u16* player_wp = (u16*)base;  base += (size_t)2 * 131072 * 2;
    u16* team_wp   = (u16*)base;  base += (size_t)2 * 524288 * 2;
    u16* pre_wp    = (u16*)base;  base += (size_t)2 * 131072 * 2;
    u16* cwb       = (u16*)base;  base += (size_t)2 * 393216 * 2;
    float* cbf     = (float*)base; base += (size_t)1536 * 4;

    // 1) weights -> hi/lo bf16 planes
    cast_split_multi<<<dim3(512, 6), 256, 0, stream>>>(
        emb_w, emb_wp, 16384,
        post_w, post_wp, 65536,
        attn_outw, outw_p, 131072,
        player_w, player_wp, 131072,
        team_w, team_wp, 524288,
        pre_w, pre_wp, 131072);

    // 2) combined qkv weights
    combine_kernel<<<dim3(256, 6), 256, 0, stream>>>(
        attn_inw, attn_inb, attn_qw, attn_kw, attn_vw,
        attn_qb, attn_kb, attn_vb, cwb, cbf);

    // 3) K1: emb + post + qkv(L0)
    fused_k1<<<512, 256, 0, stream>>>(
        x, emb_wp, emb_b, emb_g, emb_beta,
        post_wp, post_b, post_g, post_beta,
        cwb, cbf, ph, pl, qb, kb, vh);

    // 4) attention L0
    attn_kernel<<<dim3(64, 4, 4), 256, 0, stream>>>(qb, kb, vh, ofh, ofl);

    // 5) K2: out(L0)+LN+res + qkv(L1)
    fused_k2<<<512, 256, 0, stream>>>(
        ofh, ofl, outw_p, outw_p + 131072, attn_outb, attn_g, attn_beta,
        cwb + (size_t)3 * 65536, cbf + 768, ph, pl, qb, kb, vh);

    // 6) attention L1
    attn_kernel<<<dim3(64, 4, 4), 256, 0, stream>>>(qb, kb, vh, ofh, ofl);

    // 7) K3: out(L1)+LN+res + player0 + player1 + team reduce
    fused_k3<<<512, 256, 0, stream>>>(
        ofh, ofl, outw_p + 65536, outw_p + 131072 + 65536,
        attn_outb + 256, attn_g + 256, attn_beta + 256,
        player_wp, player_b, player_g, player_bt,
        x, teams0, ph, pl);

    // 8) team layers (ping-pong)
    tail_gemm<512, 512, true><<<32, 256, 0, stream>>>(
        teams0, team_wp, team_wp + 524288, team_b,
        team_g, team_beta, teams0, teams1);
    tail_gemm<512, 512, true><<<32, 256, 0, stream>>>(
        teams1, team_wp + 262144, team_wp + 524288 + 262144, team_b + 512,
        team_g + 512, team_beta + 512, teams1, teams0);

    // 9) fused pre + lnf + pred
    tail_pred<<<32, 256, 0, stream>>>(
        teams0, pre_wp, pre_wp + 131072, pre_b, pre_g, pre_beta,
        lnf_g, lnf_b, pred_w, pred_b, (float*)d_out);
}

// Round 9
// 651.557 us; speedup vs baseline: 1.2130x; 1.2130x over previous
//
#include <hip/hip_runtime.h>
#include <math.h>

// SimplePlayerModel on MI355X — Round 21.
// R20 post-mortem: fusing passes = wash (141us == sum of parts) -> launch
// overhead/A-restream never were the cost; the K-loop itself is. Counters:
// every GEMM stage runs 2 waves/SIMD (64KB LDS, 2 blocks/CU) against 8
// barrier-separated K-steps — too few waves to hide per-step latency, and
// each CU streams W once per 64-row block.
// R21: 512-thread / 128-row GEMM blocks (8 waves x 16 rows; per-wave work
// and LN shape UNCHANGED — R18 lesson). Per CU: staging loads, LDS writes,
// barriers per row HALVE; if VGPR<=128, 2 blocks/CU = 16 waves (4/SIMD).
// attn/tails/combine/cast = R13 verbatim; fusion dropped.

typedef __bf16 bf16x8 __attribute__((ext_vector_type(8)));
typedef __bf16 bf16x4 __attribute__((ext_vector_type(4)));
typedef __bf16 bf16x2 __attribute__((ext_vector_type(2)));
typedef float  f32x4  __attribute__((ext_vector_type(4)));
typedef unsigned short u16;
typedef unsigned short u16x8 __attribute__((ext_vector_type(8)));

__device__ __forceinline__ u16 f2b(float f) {            // fp32 -> bf16 RNE
    unsigned int u = __builtin_bit_cast(unsigned int, f);
    return (u16)((u + 0x7fffu + ((u >> 16) & 1u)) >> 16);
}
__device__ __forceinline__ float b2f(u16 u) {
    unsigned int v = ((unsigned int)u) << 16;
    return __builtin_bit_cast(float, v);
}
__device__ __forceinline__ bf16x8 ld2x64(const u16* p) { // two 8B LDS loads
    bf16x4 lo = *(const bf16x4*)p;
    bf16x4 hi = *(const bf16x4*)(p + 4);
    return __builtin_shufflevector(lo, hi, 0, 1, 2, 3, 4, 5, 6, 7);
}
__device__ __forceinline__ bf16x8 ld4x32(const u16* p) { // four 4B LDS loads
    bf16x2 a = *(const bf16x2*)p,     b = *(const bf16x2*)(p + 2);
    bf16x2 c = *(const bf16x2*)(p + 4), d = *(const bf16x2*)(p + 6);
    bf16x4 lo = __builtin_shufflevector(a, b, 0, 1, 2, 3);
    bf16x4 hi = __builtin_shufflevector(c, d, 0, 1, 2, 3);
    return __builtin_shufflevector(lo, hi, 0, 1, 2, 3, 4, 5, 6, 7);
}
__device__ __forceinline__ void split8(const float* __restrict__ s,
                                       bf16x8& hi, bf16x8& lo) {
    u16x8 h, l;
    #pragma unroll
    for (int j = 0; j < 8; ++j) {
        float v  = s[j];
        u16  hb  = f2b(v);
        h[j] = hb;
        l[j] = f2b(v - b2f(hb));
    }
    hi = __builtin_bit_cast(bf16x8, h);
    lo = __builtin_bit_cast(bf16x8, l);
}

// --------------------------------------------- LDS-staged bf16x3 MFMA GEMM
// 512 thr = 8 waves x 16 rows = 128 rows/block, OUT=256 cols.
// W (hi+lo) double-buffered in LDS (64KB), one barrier/kt, A ring-3.
// Per-wave shape identical to the proven 256-thr version; staging loads,
// LDS writes and barriers per row are HALVED (NC=4 chunks/thread).
// TEAM: block covers 2 batches (waves 0-3 / 4-7); 8x256 tsum in Wb.
// OMODE 3: scatter bf16 into attention layout [n][h][s][d].
template<int IN, bool LN, bool RES, bool AF32, int OMODE, bool TEAM>
__device__ __forceinline__
void gemm_body(const void* __restrict__ Xa, const void* __restrict__ Xb, int ldX,
               const u16* __restrict__ Whi, const u16* __restrict__ Wlo,
               const float* __restrict__ bias,
               const float* __restrict__ g, const float* __restrict__ beta,
               const u16* __restrict__ resh, const u16* __restrict__ resl,
               int ldRes, void* __restrict__ Y0, void* __restrict__ Y1, int ldY,
               const float* __restrict__ xmask, float* __restrict__ teams,
               u16* __restrict__ Wb)
{
    constexpr int KT = IN / 32;
    const int tid = threadIdx.x;           // 0..511
    const int wv = tid >> 6, lane = tid & 63;
    const int quad = lane >> 4, l16 = lane & 15;
    const long arow = (long)blockIdx.x * 128 + wv * 16 + l16;

    const u16* sbase[4];
    int sdst[4];
    #pragma unroll
    for (int i = 0; i < 4; ++i) {
        int cid = tid + i * 512;                  // 0..2047
        int plane = cid >> 10, nt = (cid >> 6) & 15, slot = cid & 63;
        int q = slot >> 4, c = slot & 15;
        sbase[i] = (plane ? Wlo : Whi) + (long)(nt * 16 + c) * IN + q * 8;
        sdst[i]  = (plane * 16 + nt) * 512 + slot * 8;
    }
    u16x8 wreg[4];
    auto issueW = [&](int kt) {
        #pragma unroll
        for (int i = 0; i < 4; ++i) wreg[i] = *(const u16x8*)(sbase[i] + kt * 32);
    };
    auto commitW = [&](int buf) {
        #pragma unroll
        for (int i = 0; i < 4; ++i)
            *(u16x8*)&Wb[buf * 16384 + sdst[i]] = wreg[i];
    };

    bf16x8 ah[3], al[3];
    auto loadA = [&](int kt) {
        int s = kt % 3;
        long aofs = arow * (long)ldX + kt * 32 + quad * 8;
        if constexpr (AF32) {
            float av[8];
            *(f32x4*)&av[0] = *(const f32x4*)&((const float*)Xa)[aofs];
            *(f32x4*)&av[4] = *(const f32x4*)&((const float*)Xa)[aofs + 4];
            split8(av, ah[s], al[s]);
        } else {
            ah[s] = *(const bf16x8*)&((const u16*)Xa)[aofs];
            al[s] = *(const bf16x8*)&((const u16*)Xb)[aofs];
        }
    };

    f32x4 acc[16];
    #pragma unroll
    for (int nt = 0; nt < 16; ++nt) acc[nt] = f32x4{0.f, 0.f, 0.f, 0.f};

    issueW(0);
    commitW(0);
    if (KT > 1) issueW(1);
    loadA(0);
    if (KT > 1) loadA(1);
    __syncthreads();

    #pragma unroll
    for (int kt = 0; kt < KT; ++kt) {
        if (kt + 2 < KT) loadA(kt + 2);
        const u16* wb = Wb + (kt & 1) * 16384;
        const int s = kt % 3;
        #pragma unroll
        for (int nt = 0; nt < 16; ++nt) {
            bf16x8 bhi = *(const bf16x8*)&wb[nt * 512 + lane * 8];
            bf16x8 blo = *(const bf16x8*)&wb[(16 + nt) * 512 + lane * 8];
            acc[nt] = __builtin_amdgcn_mfma_f32_16x16x32_bf16(al[s], bhi, acc[nt], 0, 0, 0);
            acc[nt] = __builtin_amdgcn_mfma_f32_16x16x32_bf16(ah[s], blo, acc[nt], 0, 0, 0);
            acc[nt] = __builtin_amdgcn_mfma_f32_16x16x32_bf16(ah[s], bhi, acc[nt], 0, 0, 0);
        }
        if (kt + 1 < KT) {
            commitW((kt + 1) & 1);
            if (kt + 2 < KT) issueW(kt + 2);
            __syncthreads();
        }
    }

    #pragma unroll
    for (int nt = 0; nt < 16; ++nt) {
        float bc = bias[nt * 16 + l16];
        #pragma unroll
        for (int r = 0; r < 4; ++r) acc[nt][r] += bc;
    }

    float mean[4], rstd[4];
    if constexpr (LN) {
        float s1[4] = {0, 0, 0, 0}, s2[4] = {0, 0, 0, 0};
        #pragma unroll
        for (int nt = 0; nt < 16; ++nt)
            #pragma unroll
            for (int r = 0; r < 4; ++r) {
                s1[r] += acc[nt][r];
                s2[r] += acc[nt][r] * acc[nt][r];
            }
        #pragma unroll
        for (int off = 1; off < 16; off <<= 1)
            #pragma unroll
            for (int r = 0; r < 4; ++r) {
                s1[r] += __shfl_xor(s1[r], off, 64);
                s2[r] += __shfl_xor(s2[r], off, 64);
            }
        #pragma unroll
        for (int r = 0; r < 4; ++r) {
            mean[r] = s1[r] * (1.0f / 256.f);
            float var = s2[r] * (1.0f / 256.f) - mean[r] * mean[r];
            rstd[r] = rsqrtf(var + 1e-5f);
        }
    }

    if constexpr (TEAM) {
        // block covers 2 batches: waves 0-3 -> batch 2b, waves 4-7 -> 2b+1
        float m[4];
        #pragma unroll
        for (int r = 0; r < 4; ++r) {
            long row = (long)blockIdx.x * 128 + wv * 16 + quad * 4 + r;
            m[r] = (xmask[row * 64 + 63] == 1.0f) ? 1.0f : 0.0f;
        }
        float ts[16];
        #pragma unroll
        for (int nt = 0; nt < 16; ++nt) {
            int col = nt * 16 + l16;
            float gc = g[col], bc2 = beta[col];
            ts[nt] = 0.f;
            #pragma unroll
            for (int r = 0; r < 4; ++r) {
                long row = (long)blockIdx.x * 128 + wv * 16 + quad * 4 + r;
                float v = (acc[nt][r] - mean[r]) * rstd[r] * gc + bc2;
                v += b2f(resh[row * ldRes + col]) + b2f(resl[row * ldRes + col]);
                ts[nt] += m[r] * v;
            }
        }
        #pragma unroll
        for (int nt = 0; nt < 16; ++nt) {
            ts[nt] += __shfl_xor(ts[nt], 16, 64);
            ts[nt] += __shfl_xor(ts[nt], 32, 64);
        }
        __syncthreads();                       // all Wb reads done
        float* tsum = (float*)Wb;              // alias: 8 x 256 floats
        if (quad == 0) {
            #pragma unroll
            for (int nt = 0; nt < 16; ++nt)
                tsum[wv * 256 + nt * 16 + l16] = ts[nt];
        }
        __syncthreads();
        {
            int h = tid >> 8, c = tid & 255;   // all 512 threads
            float tot = tsum[(h * 4 + 0) * 256 + c] + tsum[(h * 4 + 1) * 256 + c]
                      + tsum[(h * 4 + 2) * 256 + c] + tsum[(h * 4 + 3) * 256 + c];
            teams[((long)blockIdx.x * 2 + h) * 512 + c]       = tot;
            teams[((long)blockIdx.x * 2 + h) * 512 + 256 + c] = tot;
        }
        return;
    }

    #pragma unroll
    for (int nt = 0; nt < 16; ++nt) {
        int col = nt * 16 + l16;
        float gc = 1.f, bc2 = 0.f;
        if constexpr (LN) { gc = g[col]; bc2 = beta[col]; }
        #pragma unroll
        for (int r = 0; r < 4; ++r) {
            long row = (long)blockIdx.x * 128 + wv * 16 + quad * 4 + r;
            float v = acc[nt][r];
            if constexpr (LN) v = (v - mean[r]) * rstd[r] * gc + bc2;
            if constexpr (RES)
                v += b2f(resh[row * ldRes + col]) + b2f(resl[row * ldRes + col]);
            long yofs = row * ldY + col;
            if constexpr (OMODE == 0) {
                ((float*)Y0)[yofs] = v;
            } else if constexpr (OMODE == 1) {
                u16 hb = f2b(v);
                ((u16*)Y0)[yofs] = hb;
                ((u16*)Y1)[yofs] = f2b(v - b2f(hb));
            } else if constexpr (OMODE == 2) {
                ((u16*)Y0)[yofs] = f2b(v);
            } else {
                // attention layout [n][h][s][d]: n=row&63, s=row>>6
                long idx = ((long)((row & 63) * 4 + (col >> 6)) * 512
                            + (row >> 6)) * 64 + (col & 63);
                ((u16*)Y0)[idx] = f2b(v);
            }
        }
    }
}

template<int IN, bool LN, bool RES, bool AF32, int OMODE, bool TEAM>
__global__ __launch_bounds__(512)
void gemm_kernel(const void* __restrict__ Xa, const void* __restrict__ Xb, int ldX,
                 const u16* __restrict__ Whi, const u16* __restrict__ Wlo,
                 const float* __restrict__ bias,
                 const float* __restrict__ g, const float* __restrict__ beta,
                 const u16* __restrict__ resh, const u16* __restrict__ resl,
                 int ldRes, void* __restrict__ Y0, void* __restrict__ Y1, int ldY,
                 const float* __restrict__ xmask, float* __restrict__ teams)
{
    __shared__ u16 Wb[32768];
    gemm_body<IN, LN, RES, AF32, OMODE, TEAM>(Xa, Xb, ldX, Whi, Wlo, bias, g,
                                              beta, resh, resl, ldRes, Y0, Y1,
                                              ldY, xmask, teams, Wb);
}

// qkv projections: grid (256, 3); y = wsel. Writes [n][h][s][d] (OMODE 3).
__global__ __launch_bounds__(512)
void qkv_proj(const u16* __restrict__ ph, const u16* __restrict__ pl,
              const u16* __restrict__ cwL, const float* __restrict__ cb,
              u16* __restrict__ qb, u16* __restrict__ kb, u16* __restrict__ vh)
{
    __shared__ u16 Wb[32768];
    int wsel = blockIdx.y;
    const u16* whi = cwL + (long)wsel * 65536;
    const u16* wlo = cwL + 393216 + (long)wsel * 65536;
    u16* Y = (wsel == 0) ? qb : (wsel == 1) ? kb : vh;
    gemm_body<256, false, false, false, 3, false>(
        ph, pl, 256, whi, wlo, cb + wsel * 256, nullptr, nullptr,
        nullptr, nullptr, 0, Y, nullptr, 256, nullptr, nullptr, Wb);
}

// ----------------------------------------------- combined in_proj @ qkv_proj
__global__ __launch_bounds__(256)
void combine_kernel(const float* __restrict__ inw, const float* __restrict__ inb,
                    const float* __restrict__ qw, const float* __restrict__ kw,
                    const float* __restrict__ vw, const float* __restrict__ qb,
                    const float* __restrict__ kb, const float* __restrict__ vb,
                    u16* __restrict__ cw, float* __restrict__ cb)
{
    int idx = blockIdx.y, L = idx / 3, wsel = idx % 3;
    const float* Wa = inw + (long)L * 768 * 256 + wsel * 65536;
    const float* ba = inb + L * 768 + wsel * 256;
    const float* Wf = (wsel == 0 ? qw : wsel == 1 ? kw : vw) + (long)L * 65536;
    const float* bf = (wsel == 0 ? qb : wsel == 1 ? kb : vb) + L * 256;

    int o = blockIdx.x, j = threadIdx.x;
    float s = 0.f;
    for (int mm = 0; mm < 256; ++mm)
        s += Wa[o * 256 + mm] * Wf[mm * 256 + j];
    u16 hb = f2b(s);
    cw[(long)idx * 65536 + o * 256 + j] = hb;
    cw[393216 + (long)idx * 65536 + o * 256 + j] = f2b(s - b2f(hb));

    __shared__ float red[256];
    red[j] = Wa[o * 256 + j] * bf[j];
    __syncthreads();
    for (int st = 128; st > 0; st >>= 1) {
        if (j < st) red[j] += red[j + st];
        __syncthreads();
    }
    if (j == 0) cb[idx * 256 + o] = red[0] + ba[o];
}

// ------------------------------------------- fp32 -> hi/lo bf16 weight planes
__global__ __launch_bounds__(256)
void cast_split_multi(const float* s0, u16* d0, int n0,
                      const float* s1, u16* d1, int n1,
                      const float* s2, u16* d2, int n2,
                      const float* s3, u16* d3, int n3,
                      const float* s4, u16* d4, int n4,
                      const float* s5, u16* d5, int n5)
{
    const float* s; u16* d; int n;
    switch (blockIdx.y) {
        case 0: s = s0; d = d0; n = n0; break;
        case 1: s = s1; d = d1; n = n1; break;
        case 2: s = s2; d = d2; n = n2; break;
        case 3: s = s3; d = d3; n = n3; break;
        case 4: s = s4; d = d4; n = n4; break;
        default: s = s5; d = d5; n = n5; break;
    }
    int i = (blockIdx.x * 256 + threadIdx.x) * 4;
    if (i >= n) return;
    float4 v = *(const float4*)&s[i];
    ushort4 h, l;
    h.x = f2b(v.x); l.x = f2b(v.x - b2f(h.x));
    h.y = f2b(v.y); l.y = f2b(v.y - b2f(h.y));
    h.z = f2b(v.z); l.z = f2b(v.z - b2f(h.z));
    h.w = f2b(v.w); l.w = f2b(v.w - b2f(h.w));
    *(ushort4*)&d[i] = h;
    *(ushort4*)&d[n + i] = l;
}

// ------------------------------------------------------- MFMA flash attention
// R13 version (82.7us): inputs in [n][h][s][d]; V staged via LDS transpose,
// 2 barriers/tile; K fragments direct from global. Grid (64,4,4).
#define VTS 66
#define PS  68
#define EXP2SCALE 0.18033688089184986f   // 0.125 * log2(e)

__global__ __launch_bounds__(256)
void attn_kernel(const u16* __restrict__ qbuf, const u16* __restrict__ kbuf,
                 const u16* __restrict__ vh,
                 u16* __restrict__ ofh, u16* __restrict__ ofl)
{
    const int n = blockIdx.x, h = blockIdx.y, sq = blockIdx.z;
    const int tid = threadIdx.x;
    const int wv = tid >> 6, lane = tid & 63;
    const int quad = lane >> 4, l16 = lane & 15;
    const long nhb = (long)(n * 4 + h) * 32768;   // (n,h) panel base, 512x64

    __shared__ u16 Vth[64 * VTS];
    __shared__ u16 Pbh[4][32 * PS];

    bf16x8 qf[2][2];
    #pragma unroll
    for (int rt = 0; rt < 2; ++rt)
        #pragma unroll
        for (int kc = 0; kc < 2; ++kc) {
            long s = sq * 128 + wv * 32 + rt * 16 + l16;
            qf[rt][kc] = *(const bf16x8*)&qbuf[nhb + s * 64 + kc * 32 + quad * 8];
        }

    f32x4 o[2][4];
    #pragma unroll
    for (int rt = 0; rt < 2; ++rt)
        #pragma unroll
        for (int dt = 0; dt < 4; ++dt) o[rt][dt] = f32x4{0.f, 0.f, 0.f, 0.f};
    float l_run[2][4] = {{0.f, 0.f, 0.f, 0.f}, {0.f, 0.f, 0.f, 0.f}};

    for (int tb = 0; tb < 8; ++tb) {
        __syncthreads();
        // V tile stage: fully coalesced contiguous read, transpose to LDS
        for (int i = tid; i < 512; i += 256) {
            int t = i >> 3, c = i & 7;
            u16x8 hvv = *(const u16x8*)&vh[nhb + (long)(tb * 64 + t) * 64 + c * 8];
            #pragma unroll
            for (int j = 0; j < 8; ++j)
                Vth[(c * 8 + j) * VTS + t] = hvv[j];
        }
        __syncthreads();

        f32x4 sA[2][4];
        #pragma unroll
        for (int rt = 0; rt < 2; ++rt)
            #pragma unroll
            for (int tt = 0; tt < 4; ++tt) sA[rt][tt] = f32x4{0.f, 0.f, 0.f, 0.f};
        #pragma unroll
        for (int kc = 0; kc < 2; ++kc)
            #pragma unroll
            for (int tt = 0; tt < 4; ++tt) {
                bf16x8 kf = *(const bf16x8*)
                    &kbuf[nhb + (long)(tb * 64 + tt * 16 + l16) * 64
                          + kc * 32 + quad * 8];
                sA[0][tt] = __builtin_amdgcn_mfma_f32_16x16x32_bf16(
                    qf[0][kc], kf, sA[0][tt], 0, 0, 0);
                sA[1][tt] = __builtin_amdgcn_mfma_f32_16x16x32_bf16(
                    qf[1][kc], kf, sA[1][tt], 0, 0, 0);
            }

        #pragma unroll
        for (int rt = 0; rt < 2; ++rt)
            #pragma unroll
            for (int r = 0; r < 4; ++r) {
                float p0 = exp2f(sA[rt][0][r] * EXP2SCALE);
                float p1 = exp2f(sA[rt][1][r] * EXP2SCALE);
                float p2 = exp2f(sA[rt][2][r] * EXP2SCALE);
                float p3 = exp2f(sA[rt][3][r] * EXP2SCALE);
                int prow = (rt * 16 + quad * 4 + r) * PS + l16;
                Pbh[wv][prow +  0] = f2b(p0);
                Pbh[wv][prow + 16] = f2b(p1);
                Pbh[wv][prow + 32] = f2b(p2);
                Pbh[wv][prow + 48] = f2b(p3);
                l_run[rt][r] += (p0 + p1) + (p2 + p3);
            }

        #pragma unroll
        for (int kc = 0; kc < 2; ++kc) {
            bf16x8 pfh[2];
            #pragma unroll
            for (int rt = 0; rt < 2; ++rt)
                pfh[rt] = ld2x64(&Pbh[wv][(rt * 16 + l16) * PS
                                          + kc * 32 + quad * 8]);
            #pragma unroll
            for (int dt = 0; dt < 4; ++dt) {
                bf16x8 vfh = ld4x32(&Vth[(dt * 16 + l16) * VTS
                                         + kc * 32 + quad * 8]);
                o[0][dt] = __builtin_amdgcn_mfma_f32_16x16x32_bf16(
                    pfh[0], vfh, o[0][dt], 0, 0, 0);
                o[1][dt] = __builtin_amdgcn_mfma_f32_16x16x32_bf16(
                    pfh[1], vfh, o[1][dt], 0, 0, 0);
            }
        }
    }

    #pragma unroll
    for (int off = 1; off < 16; off <<= 1)
        #pragma unroll
        for (int rt = 0; rt < 2; ++rt)
            #pragma unroll
            for (int r = 0; r < 4; ++r)
                l_run[rt][r] += __shfl_xor(l_run[rt][r], off, 64);

    #pragma unroll
    for (int rt = 0; rt < 2; ++rt)
        #pragma unroll
        for (int r = 0; r < 4; ++r) {
            float inv = 1.0f / l_run[rt][r];
            long s = sq * 128 + wv * 32 + rt * 16 + quad * 4 + r;
            #pragma unroll
            for (int dt = 0; dt < 4; ++dt) {
                long idx = (s * 64 + n) * 256 + h * 64 + dt * 16 + l16;
                float val = o[rt][dt][r] * inv;
                u16 hb = f2b(val);
                ofh[idx] = hb;
                ofl[idx] = f2b(val - b2f(hb));
            }
        }
}

// ---------------------------------------- tail GEMM (512-row team layers)
template<int IN, int OUT, bool RES>
__global__ __launch_bounds__(256)
void tail_gemm(const float* __restrict__ X,
               const u16* __restrict__ Whi, const u16* __restrict__ Wlo,
               const float* __restrict__ bias,
               const float* __restrict__ g, const float* __restrict__ beta,
               const float* __restrict__ res, float* __restrict__ Y)
{
    constexpr int NTW = OUT / 64;
    constexpr int KT  = IN / 32;
    const int tid = threadIdx.x;
    const int wv = tid >> 6, lane = tid & 63;
    const int quad = lane >> 4, l16 = lane & 15;
    const int row0 = blockIdx.x * 16;
    const int colbase = wv * (OUT / 4);

    f32x4 acc[NTW];
    #pragma unroll
    for (int nt = 0; nt < NTW; ++nt) acc[nt] = f32x4{0.f, 0.f, 0.f, 0.f};

    #pragma unroll
    for (int kt = 0; kt < KT; ++kt) {
        float av[8];
        long aofs = (long)(row0 + l16) * IN + kt * 32 + quad * 8;
        *(f32x4*)&av[0] = *(const f32x4*)&X[aofs];
        *(f32x4*)&av[4] = *(const f32x4*)&X[aofs + 4];
        bf16x8 ah, al;
        split8(av, ah, al);
        #pragma unroll
        for (int nt = 0; nt < NTW; ++nt) {
            long wofs = (long)(colbase + nt * 16 + l16) * IN + kt * 32 + quad * 8;
            bf16x8 bhi = *(const bf16x8*)&Whi[wofs];
            bf16x8 blo = *(const bf16x8*)&Wlo[wofs];
            acc[nt] = __builtin_amdgcn_mfma_f32_16x16x32_bf16(al, bhi, acc[nt], 0, 0, 0);
            acc[nt] = __builtin_amdgcn_mfma_f32_16x16x32_bf16(ah, blo, acc[nt], 0, 0, 0);
            acc[nt] = __builtin_amdgcn_mfma_f32_16x16x32_bf16(ah, bhi, acc[nt], 0, 0, 0);
        }
    }

    #pragma unroll
    for (int nt = 0; nt < NTW; ++nt) {
        float bc = bias[colbase + nt * 16 + l16];
        #pragma unroll
        for (int r = 0; r < 4; ++r) acc[nt][r] += bc;
    }

    float s1[4] = {0, 0, 0, 0}, s2[4] = {0, 0, 0, 0};
    #pragma unroll
    for (int nt = 0; nt < NTW; ++nt)
        #pragma unroll
        for (int r = 0; r < 4; ++r) {
            s1[r] += acc[nt][r];
            s2[r] += acc[nt][r] * acc[nt][r];
        }
    #pragma unroll
    for (int off = 1; off < 16; off <<= 1)
        #pragma unroll
        for (int r = 0; r < 4; ++r) {
            s1[r] += __shfl_xor(s1[r], off, 64);
            s2[r] += __shfl_xor(s2[r], off, 64);
        }
    __shared__ float r1[64], r2[64];
    if (l16 == 0) {
        #pragma unroll
        for (int r = 0; r < 4; ++r) {
            r1[wv * 16 + quad * 4 + r] = s1[r];
            r2[wv * 16 + quad * 4 + r] = s2[r];
        }
    }
    __syncthreads();
    float mean[4], rstd[4];
    #pragma unroll
    for (int r = 0; r < 4; ++r) {
        int rr = quad * 4 + r;
        float t1 = r1[rr] + r1[16 + rr] + r1[32 + rr] + r1[48 + rr];
        float t2 = r2[rr] + r2[16 + rr] + r2[32 + rr] + r2[48 + rr];
        mean[r] = t1 * (1.0f / OUT);
        float var = t2 * (1.0f / OUT) - mean[r] * mean[r];
        rstd[r] = rsqrtf(var + 1e-5f);
    }
    #pragma unroll
    for (int nt = 0; nt < NTW; ++nt) {
        int col = colbase + nt * 16 + l16;
        float gc = g[col], bc2 = beta[col];
        #pragma unroll
        for (int r = 0; r < 4; ++r) {
            int row = row0 + quad * 4 + r;
            float v = (acc[nt][r] - mean[r]) * rstd[r] * gc + bc2;
            if constexpr (RES) v += res[(long)row * OUT + col];
            Y[(long)row * OUT + col] = v;
        }
    }
}

// --------------------- fused pre (512->256) + lnf + pred -> out[512] fp32
__global__ __launch_bounds__(256)
void tail_pred(const float* __restrict__ X,
               const u16* __restrict__ Whi, const u16* __restrict__ Wlo,
               const float* __restrict__ bias,
               const float* __restrict__ g, const float* __restrict__ beta,
               const float* __restrict__ lnf_g, const float* __restrict__ lnf_b,
               const float* __restrict__ pw, const float* __restrict__ pb,
               float* __restrict__ out)
{
    constexpr int IN = 512, OUT = 256, NTW = 4, KT = 16;
    const int tid = threadIdx.x;
    const int wv = tid >> 6, lane = tid & 63;
    const int quad = lane >> 4, l16 = lane & 15;
    const int row0 = blockIdx.x * 16;
    const int colbase = wv * 64;

    f32x4 acc[NTW];
    #pragma unroll
    for (int nt = 0; nt < NTW; ++nt) acc[nt] = f32x4{0.f, 0.f, 0.f, 0.f};

    #pragma unroll
    for (int kt = 0; kt < KT; ++kt) {
        float av[8];
        long aofs = (long)(row0 + l16) * IN + kt * 32 + quad * 8;
        *(f32x4*)&av[0] = *(const f32x4*)&X[aofs];
        *(f32x4*)&av[4] = *(const f32x4*)&X[aofs + 4];
        bf16x8 ah, al;
        split8(av, ah, al);
        #pragma unroll
        for (int nt = 0; nt < NTW; ++nt) {
            long wofs = (long)(colbase + nt * 16 + l16) * IN + kt * 32 + quad * 8;
            bf16x8 bhi = *(const bf16x8*)&Whi[wofs];
            bf16x8 blo = *(const bf16x8*)&Wlo[wofs];
            acc[nt] = __builtin_amdgcn_mfma_f32_16x16x32_bf16(al, bhi, acc[nt], 0, 0, 0);
            acc[nt] = __builtin_amdgcn_mfma_f32_16x16x32_bf16(ah, blo, acc[nt], 0, 0, 0);
            acc[nt] = __builtin_amdgcn_mfma_f32_16x16x32_bf16(ah, bhi, acc[nt], 0, 0, 0);
        }
    }
    #pragma unroll
    for (int nt = 0; nt < NTW; ++nt) {
        float bc = bias[colbase + nt * 16 + l16];
        #pragma unroll
        for (int r = 0; r < 4; ++r) acc[nt][r] += bc;
    }

    __shared__ float r1[64], r2[64];
    // ---- LN 1 (pre_g/pre_beta)
    float s1[4] = {0, 0, 0, 0}, s2[4] = {0, 0, 0, 0};
    #pragma unroll
    for (int nt = 0; nt < NTW; ++nt)
        #pragma unroll
        for (int r = 0; r < 4; ++r) {
            s1[r] += acc[nt][r];
            s2[r] += acc[nt][r] * acc[nt][r];
        }
    #pragma unroll
    for (int off = 1; off < 16; off <<= 1)
        #pragma unroll
        for (int r = 0; r < 4; ++r) {
            s1[r] += __shfl_xor(s1[r], off, 64);
            s2[r] += __shfl_xor(s2[r], off, 64);
        }
    if (l16 == 0)
        #pragma unroll
        for (int r = 0; r < 4; ++r) {
            r1[wv * 16 + quad * 4 + r] = s1[r];
            r2[wv * 16 + quad * 4 + r] = s2[r];
        }
    __syncthreads();
    float vv[NTW][4];
    #pragma unroll
    for (int r = 0; r < 4; ++r) {
        int rr = quad * 4 + r;
        float t1 = r1[rr] + r1[16 + rr] + r1[32 + rr] + r1[48 + rr];
        float t2 = r2[rr] + r2[16 + rr] + r2[32 + rr] + r2[48 + rr];
        float mean = t1 * (1.0f / OUT);
        float rstd = rsqrtf(t2 * (1.0f / OUT) - mean * mean + 1e-5f);
        #pragma unroll
        for (int nt = 0; nt < NTW; ++nt) {
            int col = colbase + nt * 16 + l16;
            vv[nt][r] = (acc[nt][r] - mean) * rstd * g[col] + beta[col];
        }
    }
    // ---- LN 2 (lnf)
    float u1[4] = {0, 0, 0, 0}, u2[4] = {0, 0, 0, 0};
    #pragma unroll
    for (int nt = 0; nt < NTW; ++nt)
        #pragma unroll
        for (int r = 0; r < 4; ++r) {
            u1[r] += vv[nt][r];
            u2[r] += vv[nt][r] * vv[nt][r];
        }
    #pragma unroll
    for (int off = 1; off < 16; off <<= 1)
        #pragma unroll
        for (int r = 0; r < 4; ++r) {
            u1[r] += __shfl_xor(u1[r], off, 64);
            u2[r] += __shfl_xor(u2[r], off, 64);
        }
    __syncthreads();
    if (l16 == 0)
        #pragma unroll
        for (int r = 0; r < 4; ++r) {
            r1[wv * 16 + quad * 4 + r] = u1[r];
            r2[wv * 16 + quad * 4 + r] = u2[r];
        }
    __syncthreads();
    // ---- pred dot
    float pd[4];
    #pragma unroll
    for (int r = 0; r < 4; ++r) {
        int rr = quad * 4 + r;
        float t1 = r1[rr] + r1[16 + rr] + r1[32 + rr] + r1[48 + rr];
        float t2 = r2[rr] + r2[16 + rr] + r2[32 + rr] + r2[48 + rr];
        float mean = t1 * (1.0f / OUT);
        float rstd = rsqrtf(t2 * (1.0f / OUT) - mean * mean + 1e-5f);
        pd[r] = 0.f;
        #pragma unroll
        for (int nt = 0; nt < NTW; ++nt) {
            int col = colbase + nt * 16 + l16;
            float v2 = (vv[nt][r] - mean) * rstd * lnf_g[col] + lnf_b[col];
            pd[r] += v2 * pw[col];
        }
    }
    #pragma unroll
    for (int off = 1; off < 16; off <<= 1)
        #pragma unroll
        for (int r = 0; r < 4; ++r)
            pd[r] += __shfl_xor(pd[r], off, 64);
    __syncthreads();
    if (l16 == 0)
        #pragma unroll
        for (int r = 0; r < 4; ++r)
            r1[wv * 16 + quad * 4 + r] = pd[r];
    __syncthreads();
    if (wv == 0 && l16 == 0) {
        #pragma unroll
        for (int r = 0; r < 4; ++r) {
            int rr = quad * 4 + r;
            out[row0 + rr] = r1[rr] + r1[16 + rr] + r1[32 + rr] + r1[48 + rr]
                           + pb[0];
        }
    }
}

// =========================================================================
extern "C" void kernel_launch(void* const* d_in, const int* in_sizes, int n_in,
                              void* d_out, int out_size, void* d_ws, size_t ws_size,
                              hipStream_t stream)
{
    const float* x         = (const float*)d_in[0];
    const float* emb_w     = (const float*)d_in[1];
    const float* emb_b     = (const float*)d_in[2];
    const float* emb_g     = (const float*)d_in[3];
    const float* emb_beta  = (const float*)d_in[4];
    const float* post_w    = (const float*)d_in[5];
    const float* post_b    = (const float*)d_in[6];
    const float* post_g    = (const float*)d_in[7];
    const float* post_beta = (const float*)d_in[8];
    const float* attn_qw   = (const float*)d_in[9];
    const float* attn_qb   = (const float*)d_in[10];
    const float* attn_kw   = (const float*)d_in[11];
    const float* attn_kb   = (const float*)d_in[12];
    const float* attn_vw   = (const float*)d_in[13];
    const float* attn_vb   = (const float*)d_in[14];
    const float* attn_inw  = (const float*)d_in[15];
    const float* attn_inb  = (const float*)d_in[16];
    const float* attn_outw = (const float*)d_in[17];
    const float* attn_outb = (const float*)d_in[18];
    const float* attn_g    = (const float*)d_in[19];
    const float* attn_beta = (const float*)d_in[20];
    const float* player_w  = (const float*)d_in[21];
    const float* player_b  = (const float*)d_in[22];
    const float* player_g  = (const float*)d_in[23];
    const float* player_bt = (const float*)d_in[24];
    const float* team_w    = (const float*)d_in[25];
    const float* team_b    = (const float*)d_in[26];
    const float* team_g    = (const float*)d_in[27];
    const float* team_beta = (const float*)d_in[28];
    const float* pre_w     = (const float*)d_in[29];
    const float* pre_b     = (const float*)d_in[30];
    const float* pre_g     = (const float*)d_in[31];
    const float* pre_beta  = (const float*)d_in[32];
    const float* lnf_g     = (const float*)d_in[33];
    const float* lnf_b     = (const float*)d_in[34];
    const float* pred_w    = (const float*)d_in[35];
    const float* pred_b    = (const float*)d_in[36];

    // ---- workspace layout
    char* base = (char*)d_ws;
    const size_t NR = (size_t)32768 * 256;
    u16* ph  = (u16*)base;  base += NR * 2;
    u16* pl  = (u16*)base;  base += NR * 2;
    u16* ofh = (u16*)base;  base += NR * 2;
    u16* ofl = (u16*)base;  base += NR * 2;
    u16* vh  = (u16*)base;  base += NR * 2;
    u16* qb  = (u16*)base;  base += NR * 2;
    u16* kb  = (u16*)base;  base += NR * 2;
    float* teams0 = (float*)base; base += (size_t)512 * 512 * 4;
    float* teams1 = (float*)base; base += (size_t)512 * 512 * 4;
    u16* emb_wp    = (u16*)base;  base += (size_t)2 * 16384 * 2;
    u16* post_wp   = (u16*)base;  base += (size_t)2 * 65536 * 2;
    u16* outw_p    = (u16*)base;  base += (size_t)2 * 131072 * 2;
    u16* player_wp = (u16*)base;  base += (size_t)2 * 131072 * 2;
    u16* team_wp   = (u16*)base;  base += (size_t)2 * 524288 * 2;
    u16* pre_wp    = (u16*)base;  base += (size_t)2 * 131072 * 2;
    u16* cwb       = (u16*)base;  base += (size_t)2 * 393216 * 2;
    float* cbf     = (float*)base; base += (size_t)1536 * 4;

    // 1) weights -> hi/lo bf16 planes
    cast_split_multi<<<dim3(512, 6), 256, 0, stream>>>(
        emb_w, emb_wp, 16384,
        post_w, post_wp, 65536,
        attn_outw, outw_p, 131072,
        player_w, player_wp, 131072,
        team_w, team_wp, 524288,
        pre_w, pre_wp, 131072);

    // 2) combined qkv weights
    combine_kernel<<<dim3(256, 6), 256, 0, stream>>>(
        attn_inw, attn_inb, attn_qw, attn_kw, attn_vw,
        attn_qb, attn_kb, attn_vb, cwb, cbf);

    // 3) embedding + post-embedding (128 rows/block)
    gemm_kernel<64, true, false, true, 1, false><<<256, 512, 0, stream>>>(
        x, nullptr, 64, emb_wp, emb_wp + 16384, emb_b, emb_g, emb_beta,
        nullptr, nullptr, 0, ph, pl, 256, nullptr, nullptr);
    gemm_kernel<256, true, true, false, 1, false><<<256, 512, 0, stream>>>(
        ph, pl, 256, post_wp, post_wp + 65536, post_b, post_g, post_beta,
        ph, pl, 256, ph, pl, 256, nullptr, nullptr);

    // 4) attention layers
    for (int L = 0; L < 2; ++L) {
        qkv_proj<<<dim3(256, 3), 512, 0, stream>>>(
            ph, pl, cwb + (size_t)L * 3 * 65536, cbf + L * 768, qb, kb, vh);
        attn_kernel<<<dim3(64, 4, 4), 256, 0, stream>>>(qb, kb, vh, ofh, ofl);
        gemm_kernel<256, true, true, false, 1, false><<<256, 512, 0, stream>>>(
            ofh, ofl, 256, outw_p + (size_t)L * 65536,
            outw_p + 131072 + (size_t)L * 65536, attn_outb + L * 256,
            attn_g + L * 256, attn_beta + L * 256, ph, pl, 256, ph, pl, 256,
            nullptr, nullptr);
    }

    // 5) player layer 0 (stream), player layer 1 fused with team reduce
    gemm_kernel<256, true, true, false, 1, false><<<256, 512, 0, stream>>>(
        ph, pl, 256, player_wp, player_wp + 131072, player_b,
        player_g, player_bt, ph, pl, 256, ph, pl, 256, nullptr, nullptr);
    gemm_kernel<256, true, true, false, 1, true><<<256, 512, 0, stream>>>(
        ph, pl, 256, player_wp + 65536, player_wp + 131072 + 65536,
        player_b + 256, player_g + 256, player_bt + 256, ph, pl, 256,
        nullptr, nullptr, 256, x, teams0);

    // 6) team layers (ping-pong)
    tail_gemm<512, 512, true><<<32, 256, 0, stream>>>(
        teams0, team_wp, team_wp + 524288, team_b,
        team_g, team_beta, teams0, teams1);
    tail_gemm<512, 512, true><<<32, 256, 0, stream>>>(
        teams1, team_wp + 262144, team_wp + 524288 + 262144, team_b + 512,
        team_g + 512, team_beta + 512, teams1, teams0);

    // 7) fused pre + lnf + pred
    tail_pred<<<32, 256, 0, stream>>>(
        teams0, pre_wp, pre_wp + 131072, pre_b, pre_g, pre_beta,
        lnf_g, lnf_b, pred_w, pred_b, (float*)d_out);
}

// Round 12
// 646.117 us; speedup vs baseline: 1.2233x; 1.0084x over previous
//
#include <hip/hip_runtime.h>
#include <math.h>

// SimplePlayerModel on MI355X — Round 22 (2nd resubmit; two GPU-acquisition
// timeouts, no data yet).
// R21 WIN: 745 -> 651.6us. 128-row/512-thr GEMM tiles halved per-row
// staging+barriers. Confirms model: kernels bound by per-row overhead
// amortization, not pipe saturation. Top-5 now all attn (82.8us x2).
// R22: same recipe on attn: 512 thr / 8 waves, grid (64,4,2). Per-wave
// instruction stream IDENTICAL (R18 lesson: don't change load:MFMA ratio);
// V-stage per thread halves, each (n,h) panel read by 2 blocks not 4
// (FETCH 41->~30MB). LDS 43.3KB, VGPR ~72. Rest = R21 verbatim.

typedef __bf16 bf16x8 __attribute__((ext_vector_type(8)));
typedef __bf16 bf16x4 __attribute__((ext_vector_type(4)));
typedef __bf16 bf16x2 __attribute__((ext_vector_type(2)));
typedef float  f32x4  __attribute__((ext_vector_type(4)));
typedef unsigned short u16;
typedef unsigned short u16x8 __attribute__((ext_vector_type(8)));

__device__ __forceinline__ u16 f2b(float f) {            // fp32 -> bf16 RNE
    unsigned int u = __builtin_bit_cast(unsigned int, f);
    return (u16)((u + 0x7fffu + ((u >> 16) & 1u)) >> 16);
}
__device__ __forceinline__ float b2f(u16 u) {
    unsigned int v = ((unsigned int)u) << 16;
    return __builtin_bit_cast(float, v);
}
__device__ __forceinline__ bf16x8 ld2x64(const u16* p) { // two 8B LDS loads
    bf16x4 lo = *(const bf16x4*)p;
    bf16x4 hi = *(const bf16x4*)(p + 4);
    return __builtin_shufflevector(lo, hi, 0, 1, 2, 3, 4, 5, 6, 7);
}
__device__ __forceinline__ bf16x8 ld4x32(const u16* p) { // four 4B LDS loads
    bf16x2 a = *(const bf16x2*)p,     b = *(const bf16x2*)(p + 2);
    bf16x2 c = *(const bf16x2*)(p + 4), d = *(const bf16x2*)(p + 6);
    bf16x4 lo = __builtin_shufflevector(a, b, 0, 1, 2, 3);
    bf16x4 hi = __builtin_shufflevector(c, d, 0, 1, 2, 3);
    return __builtin_shufflevector(lo, hi, 0, 1, 2, 3, 4, 5, 6, 7);
}
__device__ __forceinline__ void split8(const float* __restrict__ s,
                                       bf16x8& hi, bf16x8& lo) {
    u16x8 h, l;
    #pragma unroll
    for (int j = 0; j < 8; ++j) {
        float v  = s[j];
        u16  hb  = f2b(v);
        h[j] = hb;
        l[j] = f2b(v - b2f(hb));
    }
    hi = __builtin_bit_cast(bf16x8, h);
    lo = __builtin_bit_cast(bf16x8, l);
}

// --------------------------------------------- LDS-staged bf16x3 MFMA GEMM
// 512 thr = 8 waves x 16 rows = 128 rows/block, OUT=256 cols.
// W (hi+lo) double-buffered in LDS (64KB), one barrier/kt, A ring-3.
// TEAM: block covers 2 batches (waves 0-3 / 4-7); 8x256 tsum in Wb.
// OMODE 3: scatter bf16 into attention layout [n][h][s][d].
template<int IN, bool LN, bool RES, bool AF32, int OMODE, bool TEAM>
__device__ __forceinline__
void gemm_body(const void* __restrict__ Xa, const void* __restrict__ Xb, int ldX,
               const u16* __restrict__ Whi, const u16* __restrict__ Wlo,
               const float* __restrict__ bias,
               const float* __restrict__ g, const float* __restrict__ beta,
               const u16* __restrict__ resh, const u16* __restrict__ resl,
               int ldRes, void* __restrict__ Y0, void* __restrict__ Y1, int ldY,
               const float* __restrict__ xmask, float* __restrict__ teams,
               u16* __restrict__ Wb)
{
    constexpr int KT = IN / 32;
    const int tid = threadIdx.x;           // 0..511
    const int wv = tid >> 6, lane = tid & 63;
    const int quad = lane >> 4, l16 = lane & 15;
    const long arow = (long)blockIdx.x * 128 + wv * 16 + l16;

    const u16* sbase[4];
    int sdst[4];
    #pragma unroll
    for (int i = 0; i < 4; ++i) {
        int cid = tid + i * 512;                  // 0..2047
        int plane = cid >> 10, nt = (cid >> 6) & 15, slot = cid & 63;
        int q = slot >> 4, c = slot & 15;
        sbase[i] = (plane ? Wlo : Whi) + (long)(nt * 16 + c) * IN + q * 8;
        sdst[i]  = (plane * 16 + nt) * 512 + slot * 8;
    }
    u16x8 wreg[4];
    auto issueW = [&](int kt) {
        #pragma unroll
        for (int i = 0; i < 4; ++i) wreg[i] = *(const u16x8*)(sbase[i] + kt * 32);
    };
    auto commitW = [&](int buf) {
        #pragma unroll
        for (int i = 0; i < 4; ++i)
            *(u16x8*)&Wb[buf * 16384 + sdst[i]] = wreg[i];
    };

    bf16x8 ah[3], al[3];
    auto loadA = [&](int kt) {
        int s = kt % 3;
        long aofs = arow * (long)ldX + kt * 32 + quad * 8;
        if constexpr (AF32) {
            float av[8];
            *(f32x4*)&av[0] = *(const f32x4*)&((const float*)Xa)[aofs];
            *(f32x4*)&av[4] = *(const f32x4*)&((const float*)Xa)[aofs + 4];
            split8(av, ah[s], al[s]);
        } else {
            ah[s] = *(const bf16x8*)&((const u16*)Xa)[aofs];
            al[s] = *(const bf16x8*)&((const u16*)Xb)[aofs];
        }
    };

    f32x4 acc[16];
    #pragma unroll
    for (int nt = 0; nt < 16; ++nt) acc[nt] = f32x4{0.f, 0.f, 0.f, 0.f};

    issueW(0);
    commitW(0);
    if (KT > 1) issueW(1);
    loadA(0);
    if (KT > 1) loadA(1);
    __syncthreads();

    #pragma unroll
    for (int kt = 0; kt < KT; ++kt) {
        if (kt + 2 < KT) loadA(kt + 2);
        const u16* wb = Wb + (kt & 1) * 16384;
        const int s = kt % 3;
        #pragma unroll
        for (int nt = 0; nt < 16; ++nt) {
            bf16x8 bhi = *(const bf16x8*)&wb[nt * 512 + lane * 8];
            bf16x8 blo = *(const bf16x8*)&wb[(16 + nt) * 512 + lane * 8];
            acc[nt] = __builtin_amdgcn_mfma_f32_16x16x32_bf16(al[s], bhi, acc[nt], 0, 0, 0);
            acc[nt] = __builtin_amdgcn_mfma_f32_16x16x32_bf16(ah[s], blo, acc[nt], 0, 0, 0);
            acc[nt] = __builtin_amdgcn_mfma_f32_16x16x32_bf16(ah[s], bhi, acc[nt], 0, 0, 0);
        }
        if (kt + 1 < KT) {
            commitW((kt + 1) & 1);
            if (kt + 2 < KT) issueW(kt + 2);
            __syncthreads();
        }
    }

    #pragma unroll
    for (int nt = 0; nt < 16; ++nt) {
        float bc = bias[nt * 16 + l16];
        #pragma unroll
        for (int r = 0; r < 4; ++r) acc[nt][r] += bc;
    }

    float mean[4], rstd[4];
    if constexpr (LN) {
        float s1[4] = {0, 0, 0, 0}, s2[4] = {0, 0, 0, 0};
        #pragma unroll
        for (int nt = 0; nt < 16; ++nt)
            #pragma unroll
            for (int r = 0; r < 4; ++r) {
                s1[r] += acc[nt][r];
                s2[r] += acc[nt][r] * acc[nt][r];
            }
        #pragma unroll
        for (int off = 1; off < 16; off <<= 1)
            #pragma unroll
            for (int r = 0; r < 4; ++r) {
                s1[r] += __shfl_xor(s1[r], off, 64);
                s2[r] += __shfl_xor(s2[r], off, 64);
            }
        #pragma unroll
        for (int r = 0; r < 4; ++r) {
            mean[r] = s1[r] * (1.0f / 256.f);
            float var = s2[r] * (1.0f / 256.f) - mean[r] * mean[r];
            rstd[r] = rsqrtf(var + 1e-5f);
        }
    }

    if constexpr (TEAM) {
        // block covers 2 batches: waves 0-3 -> batch 2b, waves 4-7 -> 2b+1
        float m[4];
        #pragma unroll
        for (int r = 0; r < 4; ++r) {
            long row = (long)blockIdx.x * 128 + wv * 16 + quad * 4 + r;
            m[r] = (xmask[row * 64 + 63] == 1.0f) ? 1.0f : 0.0f;
        }
        float ts[16];
        #pragma unroll
        for (int nt = 0; nt < 16; ++nt) {
            int col = nt * 16 + l16;
            float gc = g[col], bc2 = beta[col];
            ts[nt] = 0.f;
            #pragma unroll
            for (int r = 0; r < 4; ++r) {
                long row = (long)blockIdx.x * 128 + wv * 16 + quad * 4 + r;
                float v = (acc[nt][r] - mean[r]) * rstd[r] * gc + bc2;
                v += b2f(resh[row * ldRes + col]) + b2f(resl[row * ldRes + col]);
                ts[nt] += m[r] * v;
            }
        }
        #pragma unroll
        for (int nt = 0; nt < 16; ++nt) {
            ts[nt] += __shfl_xor(ts[nt], 16, 64);
            ts[nt] += __shfl_xor(ts[nt], 32, 64);
        }
        __syncthreads();                       // all Wb reads done
        float* tsum = (float*)Wb;              // alias: 8 x 256 floats
        if (quad == 0) {
            #pragma unroll
            for (int nt = 0; nt < 16; ++nt)
                tsum[wv * 256 + nt * 16 + l16] = ts[nt];
        }
        __syncthreads();
        {
            int h = tid >> 8, c = tid & 255;   // all 512 threads
            float tot = tsum[(h * 4 + 0) * 256 + c] + tsum[(h * 4 + 1) * 256 + c]
                      + tsum[(h * 4 + 2) * 256 + c] + tsum[(h * 4 + 3) * 256 + c];
            teams[((long)blockIdx.x * 2 + h) * 512 + c]       = tot;
            teams[((long)blockIdx.x * 2 + h) * 512 + 256 + c] = tot;
        }
        return;
    }

    #pragma unroll
    for (int nt = 0; nt < 16; ++nt) {
        int col = nt * 16 + l16;
        float gc = 1.f, bc2 = 0.f;
        if constexpr (LN) { gc = g[col]; bc2 = beta[col]; }
        #pragma unroll
        for (int r = 0; r < 4; ++r) {
            long row = (long)blockIdx.x * 128 + wv * 16 + quad * 4 + r;
            float v = acc[nt][r];
            if constexpr (LN) v = (v - mean[r]) * rstd[r] * gc + bc2;
            if constexpr (RES)
                v += b2f(resh[row * ldRes + col]) + b2f(resl[row * ldRes + col]);
            long yofs = row * ldY + col;
            if constexpr (OMODE == 0) {
                ((float*)Y0)[yofs] = v;
            } else if constexpr (OMODE == 1) {
                u16 hb = f2b(v);
                ((u16*)Y0)[yofs] = hb;
                ((u16*)Y1)[yofs] = f2b(v - b2f(hb));
            } else if constexpr (OMODE == 2) {
                ((u16*)Y0)[yofs] = f2b(v);
            } else {
                // attention layout [n][h][s][d]: n=row&63, s=row>>6
                long idx = ((long)((row & 63) * 4 + (col >> 6)) * 512
                            + (row >> 6)) * 64 + (col & 63);
                ((u16*)Y0)[idx] = f2b(v);
            }
        }
    }
}

template<int IN, bool LN, bool RES, bool AF32, int OMODE, bool TEAM>
__global__ __launch_bounds__(512)
void gemm_kernel(const void* __restrict__ Xa, const void* __restrict__ Xb, int ldX,
                 const u16* __restrict__ Whi, const u16* __restrict__ Wlo,
                 const float* __restrict__ bias,
                 const float* __restrict__ g, const float* __restrict__ beta,
                 const u16* __restrict__ resh, const u16* __restrict__ resl,
                 int ldRes, void* __restrict__ Y0, void* __restrict__ Y1, int ldY,
                 const float* __restrict__ xmask, float* __restrict__ teams)
{
    __shared__ u16 Wb[32768];
    gemm_body<IN, LN, RES, AF32, OMODE, TEAM>(Xa, Xb, ldX, Whi, Wlo, bias, g,
                                              beta, resh, resl, ldRes, Y0, Y1,
                                              ldY, xmask, teams, Wb);
}

// qkv projections: grid (256, 3); y = wsel. Writes [n][h][s][d] (OMODE 3).
__global__ __launch_bounds__(512)
void qkv_proj(const u16* __restrict__ ph, const u16* __restrict__ pl,
              const u16* __restrict__ cwL, const float* __restrict__ cb,
              u16* __restrict__ qb, u16* __restrict__ kb, u16* __restrict__ vh)
{
    __shared__ u16 Wb[32768];
    int wsel = blockIdx.y;
    const u16* whi = cwL + (long)wsel * 65536;
    const u16* wlo = cwL + 393216 + (long)wsel * 65536;
    u16* Y = (wsel == 0) ? qb : (wsel == 1) ? kb : vh;
    gemm_body<256, false, false, false, 3, false>(
        ph, pl, 256, whi, wlo, cb + wsel * 256, nullptr, nullptr,
        nullptr, nullptr, 0, Y, nullptr, 256, nullptr, nullptr, Wb);
}

// ----------------------------------------------- combined in_proj @ qkv_proj
__global__ __launch_bounds__(256)
void combine_kernel(const float* __restrict__ inw, const float* __restrict__ inb,
                    const float* __restrict__ qw, const float* __restrict__ kw,
                    const float* __restrict__ vw, const float* __restrict__ qb,
                    const float* __restrict__ kb, const float* __restrict__ vb,
                    u16* __restrict__ cw, float* __restrict__ cb)
{
    int idx = blockIdx.y, L = idx / 3, wsel = idx % 3;
    const float* Wa = inw + (long)L * 768 * 256 + wsel * 65536;
    const float* ba = inb + L * 768 + wsel * 256;
    const float* Wf = (wsel == 0 ? qw : wsel == 1 ? kw : vw) + (long)L * 65536;
    const float* bf = (wsel == 0 ? qb : wsel == 1 ? kb : vb) + L * 256;

    int o = blockIdx.x, j = threadIdx.x;
    float s = 0.f;
    for (int mm = 0; mm < 256; ++mm)
        s += Wa[o * 256 + mm] * Wf[mm * 256 + j];
    u16 hb = f2b(s);
    cw[(long)idx * 65536 + o * 256 + j] = hb;
    cw[393216 + (long)idx * 65536 + o * 256 + j] = f2b(s - b2f(hb));

    __shared__ float red[256];
    red[j] = Wa[o * 256 + j] * bf[j];
    __syncthreads();
    for (int st = 128; st > 0; st >>= 1) {
        if (j < st) red[j] += red[j + st];
        __syncthreads();
    }
    if (j == 0) cb[idx * 256 + o] = red[0] + ba[o];
}

// ------------------------------------------- fp32 -> hi/lo bf16 weight planes
__global__ __launch_bounds__(256)
void cast_split_multi(const float* s0, u16* d0, int n0,
                      const float* s1, u16* d1, int n1,
                      const float* s2, u16* d2, int n2,
                      const float* s3, u16* d3, int n3,
                      const float* s4, u16* d4, int n4,
                      const float* s5, u16* d5, int n5)
{
    const float* s; u16* d; int n;
    switch (blockIdx.y) {
        case 0: s = s0; d = d0; n = n0; break;
        case 1: s = s1; d = d1; n = n1; break;
        case 2: s = s2; d = d2; n = n2; break;
        case 3: s = s3; d = d3; n = n3; break;
        case 4: s = s4; d = d4; n = n4; break;
        default: s = s5; d = d5; n = n5; break;
    }
    int i = (blockIdx.x * 256 + threadIdx.x) * 4;
    if (i >= n) return;
    float4 v = *(const float4*)&s[i];
    ushort4 h, l;
    h.x = f2b(v.x); l.x = f2b(v.x - b2f(h.x));
    h.y = f2b(v.y); l.y = f2b(v.y - b2f(h.y));
    h.z = f2b(v.z); l.z = f2b(v.z - b2f(h.z));
    h.w = f2b(v.w); l.w = f2b(v.w - b2f(h.w));
    *(ushort4*)&d[i] = h;
    *(ushort4*)&d[n + i] = l;
}

// ------------------------------------------------------- MFMA flash attention
// R22: 512 thr / 8 waves, grid (64,4,2); 256 q rows/block, 32 rows/wave
// (per-wave stream identical to R13). V staged once per block for 8 waves
// (1 u16x8 load/thread/tile); K fragments direct from global.
#define VTS 66
#define PS  68
#define EXP2SCALE 0.18033688089184986f   // 0.125 * log2(e)

__global__ __launch_bounds__(512)
void attn_kernel(const u16* __restrict__ qbuf, const u16* __restrict__ kbuf,
                 const u16* __restrict__ vh,
                 u16* __restrict__ ofh, u16* __restrict__ ofl)
{
    const int n = blockIdx.x, h = blockIdx.y, sq = blockIdx.z;
    const int tid = threadIdx.x;           // 0..511
    const int wv = tid >> 6, lane = tid & 63;
    const int quad = lane >> 4, l16 = lane & 15;
    const long nhb = (long)(n * 4 + h) * 32768;   // (n,h) panel base, 512x64

    __shared__ u16 Vth[64 * VTS];          // 8448 B
    __shared__ u16 Pbh[8][32 * PS];        // 34816 B

    bf16x8 qf[2][2];
    #pragma unroll
    for (int rt = 0; rt < 2; ++rt)
        #pragma unroll
        for (int kc = 0; kc < 2; ++kc) {
            long s = sq * 256 + wv * 32 + rt * 16 + l16;
            qf[rt][kc] = *(const bf16x8*)&qbuf[nhb + s * 64 + kc * 32 + quad * 8];
        }

    f32x4 o[2][4];
    #pragma unroll
    for (int rt = 0; rt < 2; ++rt)
        #pragma unroll
        for (int dt = 0; dt < 4; ++dt) o[rt][dt] = f32x4{0.f, 0.f, 0.f, 0.f};
    float l_run[2][4] = {{0.f, 0.f, 0.f, 0.f}, {0.f, 0.f, 0.f, 0.f}};

    const int vt = tid >> 3, vc = tid & 7;   // V stage: 1 chunk/thread

    for (int tb = 0; tb < 8; ++tb) {
        __syncthreads();
        // V tile stage: 512 threads cover 512 chunks (1 load each)
        {
            u16x8 hvv = *(const u16x8*)&vh[nhb + (long)(tb * 64 + vt) * 64 + vc * 8];
            #pragma unroll
            for (int j = 0; j < 8; ++j)
                Vth[(vc * 8 + j) * VTS + vt] = hvv[j];
        }
        __syncthreads();

        f32x4 sA[2][4];
        #pragma unroll
        for (int rt = 0; rt < 2; ++rt)
            #pragma unroll
            for (int tt = 0; tt < 4; ++tt) sA[rt][tt] = f32x4{0.f, 0.f, 0.f, 0.f};
        #pragma unroll
        for (int kc = 0; kc < 2; ++kc)
            #pragma unroll
            for (int tt = 0; tt < 4; ++tt) {
                bf16x8 kf = *(const bf16x8*)
                    &kbuf[nhb + (long)(tb * 64 + tt * 16 + l16) * 64
                          + kc * 32 + quad * 8];
                sA[0][tt] = __builtin_amdgcn_mfma_f32_16x16x32_bf16(
                    qf[0][kc], kf, sA[0][tt], 0, 0, 0);
                sA[1][tt] = __builtin_amdgcn_mfma_f32_16x16x32_bf16(
                    qf[1][kc], kf, sA[1][tt], 0, 0, 0);
            }

        #pragma unroll
        for (int rt = 0; rt < 2; ++rt)
            #pragma unroll
            for (int r = 0; r < 4; ++r) {
                float p0 = exp2f(sA[rt][0][r] * EXP2SCALE);
                float p1 = exp2f(sA[rt][1][r] * EXP2SCALE);
                float p2 = exp2f(sA[rt][2][r] * EXP2SCALE);
                float p3 = exp2f(sA[rt][3][r] * EXP2SCALE);
                int prow = (rt * 16 + quad * 4 + r) * PS + l16;
                Pbh[wv][prow +  0] = f2b(p0);
                Pbh[wv][prow + 16] = f2b(p1);
                Pbh[wv][prow + 32] = f2b(p2);
                Pbh[wv][prow + 48] = f2b(p3);
                l_run[rt][r] += (p0 + p1) + (p2 + p3);
            }

        #pragma unroll
        for (int kc = 0; kc < 2; ++kc) {
            bf16x8 pfh[2];
            #pragma unroll
            for (int rt = 0; rt < 2; ++rt)
                pfh[rt] = ld2x64(&Pbh[wv][(rt * 16 + l16) * PS
                                          + kc * 32 + quad * 8]);
            #pragma unroll
            for (int dt = 0; dt < 4; ++dt) {
                bf16x8 vfh = ld4x32(&Vth[(dt * 16 + l16) * VTS
                                         + kc * 32 + quad * 8]);
                o[0][dt] = __builtin_amdgcn_mfma_f32_16x16x32_bf16(
                    pfh[0], vfh, o[0][dt], 0, 0, 0);
                o[1][dt] = __builtin_amdgcn_mfma_f32_16x16x32_bf16(
                    pfh[1], vfh, o[1][dt], 0, 0, 0);
            }
        }
    }

    #pragma unroll
    for (int off = 1; off < 16; off <<= 1)
        #pragma unroll
        for (int rt = 0; rt < 2; ++rt)
            #pragma unroll
            for (int r = 0; r < 4; ++r)
                l_run[rt][r] += __shfl_xor(l_run[rt][r], off, 64);

    #pragma unroll
    for (int rt = 0; rt < 2; ++rt)
        #pragma unroll
        for (int r = 0; r < 4; ++r) {
            float inv = 1.0f / l_run[rt][r];
            long s = sq * 256 + wv * 32 + rt * 16 + quad * 4 + r;
            #pragma unroll
            for (int dt = 0; dt < 4; ++dt) {
                long idx = (s * 64 + n) * 256 + h * 64 + dt * 16 + l16;
                float val = o[rt][dt][r] * inv;
                u16 hb = f2b(val);
                ofh[idx] = hb;
                ofl[idx] = f2b(val - b2f(hb));
            }
        }
}

// ---------------------------------------- tail GEMM (512-row team layers)
template<int IN, int OUT, bool RES>
__global__ __launch_bounds__(256)
void tail_gemm(const float* __restrict__ X,
               const u16* __restrict__ Whi, const u16* __restrict__ Wlo,
               const float* __restrict__ bias,
               const float* __restrict__ g, const float* __restrict__ beta,
               const float* __restrict__ res, float* __restrict__ Y)
{
    constexpr int NTW = OUT / 64;
    constexpr int KT  = IN / 32;
    const int tid = threadIdx.x;
    const int wv = tid >> 6, lane = tid & 63;
    const int quad = lane >> 4, l16 = lane & 15;
    const int row0 = blockIdx.x * 16;
    const int colbase = wv * (OUT / 4);

    f32x4 acc[NTW];
    #pragma unroll
    for (int nt = 0; nt < NTW; ++nt) acc[nt] = f32x4{0.f, 0.f, 0.f, 0.f};

    #pragma unroll
    for (int kt = 0; kt < KT; ++kt) {
        float av[8];
        long aofs = (long)(row0 + l16) * IN + kt * 32 + quad * 8;
        *(f32x4*)&av[0] = *(const f32x4*)&X[aofs];
        *(f32x4*)&av[4] = *(const f32x4*)&X[aofs + 4];
        bf16x8 ah, al;
        split8(av, ah, al);
        #pragma unroll
        for (int nt = 0; nt < NTW; ++nt) {
            long wofs = (long)(colbase + nt * 16 + l16) * IN + kt * 32 + quad * 8;
            bf16x8 bhi = *(const bf16x8*)&Whi[wofs];
            bf16x8 blo = *(const bf16x8*)&Wlo[wofs];
            acc[nt] = __builtin_amdgcn_mfma_f32_16x16x32_bf16(al, bhi, acc[nt], 0, 0, 0);
            acc[nt] = __builtin_amdgcn_mfma_f32_16x16x32_bf16(ah, blo, acc[nt], 0, 0, 0);
            acc[nt] = __builtin_amdgcn_mfma_f32_16x16x32_bf16(ah, bhi, acc[nt], 0, 0, 0);
        }
    }

    #pragma unroll
    for (int nt = 0; nt < NTW; ++nt) {
        float bc = bias[colbase + nt * 16 + l16];
        #pragma unroll
        for (int r = 0; r < 4; ++r) acc[nt][r] += bc;
    }

    float s1[4] = {0, 0, 0, 0}, s2[4] = {0, 0, 0, 0};
    #pragma unroll
    for (int nt = 0; nt < NTW; ++nt)
        #pragma unroll
        for (int r = 0; r < 4; ++r) {
            s1[r] += acc[nt][r];
            s2[r] += acc[nt][r] * acc[nt][r];
        }
    #pragma unroll
    for (int off = 1; off < 16; off <<= 1)
        #pragma unroll
        for (int r = 0; r < 4; ++r) {
            s1[r] += __shfl_xor(s1[r], off, 64);
            s2[r] += __shfl_xor(s2[r], off, 64);
        }
    __shared__ float r1[64], r2[64];
    if (l16 == 0) {
        #pragma unroll
        for (int r = 0; r < 4; ++r) {
            r1[wv * 16 + quad * 4 + r] = s1[r];
            r2[wv * 16 + quad * 4 + r] = s2[r];
        }
    }
    __syncthreads();
    float mean[4], rstd[4];
    #pragma unroll
    for (int r = 0; r < 4; ++r) {
        int rr = quad * 4 + r;
        float t1 = r1[rr] + r1[16 + rr] + r1[32 + rr] + r1[48 + rr];
        float t2 = r2[rr] + r2[16 + rr] + r2[32 + rr] + r2[48 + rr];
        mean[r] = t1 * (1.0f / OUT);
        float var = t2 * (1.0f / OUT) - mean[r] * mean[r];
        rstd[r] = rsqrtf(var + 1e-5f);
    }
    #pragma unroll
    for (int nt = 0; nt < NTW; ++nt) {
        int col = colbase + nt * 16 + l16;
        float gc = g[col], bc2 = beta[col];
        #pragma unroll
        for (int r = 0; r < 4; ++r) {
            int row = row0 + quad * 4 + r;
            float v = (acc[nt][r] - mean[r]) * rstd[r] * gc + bc2;
            if constexpr (RES) v += res[(long)row * OUT + col];
            Y[(long)row * OUT + col] = v;
        }
    }
}

// --------------------- fused pre (512->256) + lnf + pred -> out[512] fp32
__global__ __launch_bounds__(256)
void tail_pred(const float* __restrict__ X,
               const u16* __restrict__ Whi, const u16* __restrict__ Wlo,
               const float* __restrict__ bias,
               const float* __restrict__ g, const float* __restrict__ beta,
               const float* __restrict__ lnf_g, const float* __restrict__ lnf_b,
               const float* __restrict__ pw, const float* __restrict__ pb,
               float* __restrict__ out)
{
    constexpr int IN = 512, OUT = 256, NTW = 4, KT = 16;
    const int tid = threadIdx.x;
    const int wv = tid >> 6, lane = tid & 63;
    const int quad = lane >> 4, l16 = lane & 15;
    const int row0 = blockIdx.x * 16;
    const int colbase = wv * 64;

    f32x4 acc[NTW];
    #pragma unroll
    for (int nt = 0; nt < NTW; ++nt) acc[nt] = f32x4{0.f, 0.f, 0.f, 0.f};

    #pragma unroll
    for (int kt = 0; kt < KT; ++kt) {
        float av[8];
        long aofs = (long)(row0 + l16) * IN + kt * 32 + quad * 8;
        *(f32x4*)&av[0] = *(const f32x4*)&X[aofs];
        *(f32x4*)&av[4] = *(const f32x4*)&X[aofs + 4];
        bf16x8 ah, al;
        split8(av, ah, al);
        #pragma unroll
        for (int nt = 0; nt < NTW; ++nt) {
            long wofs = (long)(colbase + nt * 16 + l16) * IN + kt * 32 + quad * 8;
            bf16x8 bhi = *(const bf16x8*)&Whi[wofs];
            bf16x8 blo = *(const bf16x8*)&Wlo[wofs];
            acc[nt] = __builtin_amdgcn_mfma_f32_16x16x32_bf16(al, bhi, acc[nt], 0, 0, 0);
            acc[nt] = __builtin_amdgcn_mfma_f32_16x16x32_bf16(ah, blo, acc[nt], 0, 0, 0);
            acc[nt] = __builtin_amdgcn_mfma_f32_16x16x32_bf16(ah, bhi, acc[nt], 0, 0, 0);
        }
    }
    #pragma unroll
    for (int nt = 0; nt < NTW; ++nt) {
        float bc = bias[colbase + nt * 16 + l16];
        #pragma unroll
        for (int r = 0; r < 4; ++r) acc[nt][r] += bc;
    }

    __shared__ float r1[64], r2[64];
    // ---- LN 1 (pre_g/pre_beta)
    float s1[4] = {0, 0, 0, 0}, s2[4] = {0, 0, 0, 0};
    #pragma unroll
    for (int nt = 0; nt < NTW; ++nt)
        #pragma unroll
        for (int r = 0; r < 4; ++r) {
            s1[r] += acc[nt][r];
            s2[r] += acc[nt][r] * acc[nt][r];
        }
    #pragma unroll
    for (int off = 1; off < 16; off <<= 1)
        #pragma unroll
        for (int r = 0; r < 4; ++r) {
            s1[r] += __shfl_xor(s1[r], off, 64);
            s2[r] += __shfl_xor(s2[r], off, 64);
        }
    if (l16 == 0)
        #pragma unroll
        for (int r = 0; r < 4; ++r) {
            r1[wv * 16 + quad * 4 + r] = s1[r];
            r2[wv * 16 + quad * 4 + r] = s2[r];
        }
    __syncthreads();
    float vv[NTW][4];
    #pragma unroll
    for (int r = 0; r < 4; ++r) {
        int rr = quad * 4 + r;
        float t1 = r1[rr] + r1[16 + rr] + r1[32 + rr] + r1[48 + rr];
        float t2 = r2[rr] + r2[16 + rr] + r2[32 + rr] + r2[48 + rr];
        float mean = t1 * (1.0f / OUT);
        float rstd = rsqrtf(t2 * (1.0f / OUT) - mean * mean + 1e-5f);
        #pragma unroll
        for (int nt = 0; nt < NTW; ++nt) {
            int col = colbase + nt * 16 + l16;
            vv[nt][r] = (acc[nt][r] - mean) * rstd * g[col] + beta[col];
        }
    }
    // ---- LN 2 (lnf)
    float u1[4] = {0, 0, 0, 0}, u2[4] = {0, 0, 0, 0};
    #pragma unroll
    for (int nt = 0; nt < NTW; ++nt)
        #pragma unroll
        for (int r = 0; r < 4; ++r) {
            u1[r] += vv[nt][r];
            u2[r] += vv[nt][r] * vv[nt][r];
        }
    #pragma unroll
    for (int off = 1; off < 16; off <<= 1)
        #pragma unroll
        for (int r = 0; r < 4; ++r) {
            u1[r] += __shfl_xor(u1[r], off, 64);
            u2[r] += __shfl_xor(u2[r], off, 64);
        }
    __syncthreads();
    if (l16 == 0)
        #pragma unroll
        for (int r = 0; r < 4; ++r) {
            r1[wv * 16 + quad * 4 + r] = u1[r];
            r2[wv * 16 + quad * 4 + r] = u2[r];
        }
    __syncthreads();
    // ---- pred dot
    float pd[4];
    #pragma unroll
    for (int r = 0; r < 4; ++r) {
        int rr = quad * 4 + r;
        float t1 = r1[rr] + r1[16 + rr] + r1[32 + rr] + r1[48 + rr];
        float t2 = r2[rr] + r2[16 + rr] + r2[32 + rr] + r2[48 + rr];
        float mean = t1 * (1.0f / OUT);
        float rstd = rsqrtf(t2 * (1.0f / OUT) - mean * mean + 1e-5f);
        pd[r] = 0.f;
        #pragma unroll
        for (int nt = 0; nt < NTW; ++nt) {
            int col = colbase + nt * 16 + l16;
            float v2 = (vv[nt][r] - mean) * rstd * lnf_g[col] + lnf_b[col];
            pd[r] += v2 * pw[col];
        }
    }
    #pragma unroll
    for (int off = 1; off < 16; off <<= 1)
        #pragma unroll
        for (int r = 0; r < 4; ++r)
            pd[r] += __shfl_xor(pd[r], off, 64);
    __syncthreads();
    if (l16 == 0)
        #pragma unroll
        for (int r = 0; r < 4; ++r)
            r1[wv * 16 + quad * 4 + r] = pd[r];
    __syncthreads();
    if (wv == 0 && l16 == 0) {
        #pragma unroll
        for (int r = 0; r < 4; ++r) {
            int rr = quad * 4 + r;
            out[row0 + rr] = r1[rr] + r1[16 + rr] + r1[32 + rr] + r1[48 + rr]
                           + pb[0];
        }
    }
}

// =========================================================================
extern "C" void kernel_launch(void* const* d_in, const int* in_sizes, int n_in,
                              void* d_out, int out_size, void* d_ws, size_t ws_size,
                              hipStream_t stream)
{
    const float* x         = (const float*)d_in[0];
    const float* emb_w     = (const float*)d_in[1];
    const float* emb_b     = (const float*)d_in[2];
    const float* emb_g     = (const float*)d_in[3];
    const float* emb_beta  = (const float*)d_in[4];
    const float* post_w    = (const float*)d_in[5];
    const float* post_b    = (const float*)d_in[6];
    const float* post_g    = (const float*)d_in[7];
    const float* post_beta = (const float*)d_in[8];
    const float* attn_qw   = (const float*)d_in[9];
    const float* attn_qb   = (const float*)d_in[10];
    const float* attn_kw   = (const float*)d_in[11];
    const float* attn_kb   = (const float*)d_in[12];
    const float* attn_vw   = (const float*)d_in[13];
    const float* attn_vb   = (const float*)d_in[14];
    const float* attn_inw  = (const float*)d_in[15];
    const float* attn_inb  = (const float*)d_in[16];
    const float* attn_outw = (const float*)d_in[17];
    const float* attn_outb = (const float*)d_in[18];
    const float* attn_g    = (const float*)d_in[19];
    const float* attn_beta = (const float*)d_in[20];
    const float* player_w  = (const float*)d_in[21];
    const float* player_b  = (const float*)d_in[22];
    const float* player_g  = (const float*)d_in[23];
    const float* player_bt = (const float*)d_in[24];
    const float* team_w    = (const float*)d_in[25];
    const float* team_b    = (const float*)d_in[26];
    const float* team_g    = (const float*)d_in[27];
    const float* team_beta = (const float*)d_in[28];
    const float* pre_w     = (const float*)d_in[29];
    const float* pre_b     = (const float*)d_in[30];
    const float* pre_g     = (const float*)d_in[31];
    const float* pre_beta  = (const float*)d_in[32];
    const float* lnf_g     = (const float*)d_in[33];
    const float* lnf_b     = (const float*)d_in[34];
    const float* pred_w    = (const float*)d_in[35];
    const float* pred_b    = (const float*)d_in[36];

    // ---- workspace layout
    char* base = (char*)d_ws;
    const size_t NR = (size_t)32768 * 256;
    u16* ph  = (u16*)base;  base += NR * 2;
    u16* pl  = (u16*)base;  base += NR * 2;
    u16* ofh = (u16*)base;  base += NR * 2;
    u16* ofl = (u16*)base;  base += NR * 2;
    u16* vh  = (u16*)base;  base += NR * 2;
    u16* qb  = (u16*)base;  base += NR * 2;
    u16* kb  = (u16*)base;  base += NR * 2;
    float* teams0 = (float*)base; base += (size_t)512 * 512 * 4;
    float* teams1 = (float*)base; base += (size_t)512 * 512 * 4;
    u16* emb_wp    = (u16*)base;  base += (size_t)2 * 16384 * 2;
    u16* post_wp   = (u16*)base;  base += (size_t)2 * 65536 * 2;
    u16* outw_p    = (u16*)base;  base += (size_t)2 * 131072 * 2;
    u16* player_wp = (u16*)base;  base += (size_t)2 * 131072 * 2;
    u16* team_wp   = (u16*)base;  base += (size_t)2 * 524288 * 2;
    u16* pre_wp    = (u16*)base;  base += (size_t)2 * 131072 * 2;
    u16* cwb       = (u16*)base;  base += (size_t)2 * 393216 * 2;
    float* cbf     = (float*)base; base += (size_t)1536 * 4;

    // 1) weights -> hi/lo bf16 planes
    cast_split_multi<<<dim3(512, 6), 256, 0, stream>>>(
        emb_w, emb_wp, 16384,
        post_w, post_wp, 65536,
        attn_outw, outw_p, 131072,
        player_w, player_wp, 131072,
        team_w, team_wp, 524288,
        pre_w, pre_wp, 131072);

    // 2) combined qkv weights
    combine_kernel<<<dim3(256, 6), 256, 0, stream>>>(
        attn_inw, attn_inb, attn_qw, attn_kw, attn_vw,
        attn_qb, attn_kb, attn_vb, cwb, cbf);

    // 3) embedding + post-embedding (128 rows/block)
    gemm_kernel<64, true, false, true, 1, false><<<256, 512, 0, stream>>>(
        x, nullptr, 64, emb_wp, emb_wp + 16384, emb_b, emb_g, emb_beta,
        nullptr, nullptr, 0, ph, pl, 256, nullptr, nullptr);
    gemm_kernel<256, true, true, false, 1, false><<<256, 512, 0, stream>>>(
        ph, pl, 256, post_wp, post_wp + 65536, post_b, post_g, post_beta,
        ph, pl, 256, ph, pl, 256, nullptr, nullptr);

    // 4) attention layers
    for (int L = 0; L < 2; ++L) {
        qkv_proj<<<dim3(256, 3), 512, 0, stream>>>(
            ph, pl, cwb + (size_t)L * 3 * 65536, cbf + L * 768, qb, kb, vh);
        attn_kernel<<<dim3(64, 4, 2), 512, 0, stream>>>(qb, kb, vh, ofh, ofl);
        gemm_kernel<256, true, true, false, 1, false><<<256, 512, 0, stream>>>(
            ofh, ofl, 256, outw_p + (size_t)L * 65536,
            outw_p + 131072 + (size_t)L * 65536, attn_outb + L * 256,
            attn_g + L * 256, attn_beta + L * 256, ph, pl, 256, ph, pl, 256,
            nullptr, nullptr);
    }

    // 5) player layer 0 (stream), player layer 1 fused with team reduce
    gemm_kernel<256, true, true, false, 1, false><<<256, 512, 0, stream>>>(
        ph, pl, 256, player_wp, player_wp + 131072, player_b,
        player_g, player_bt, ph, pl, 256, ph, pl, 256, nullptr, nullptr);
    gemm_kernel<256, true, true, false, 1, true><<<256, 512, 0, stream>>>(
        ph, pl, 256, player_wp + 65536, player_wp + 131072 + 65536,
        player_b + 256, player_g + 256, player_bt + 256, ph, pl, 256,
        nullptr, nullptr, 256, x, teams0);

    // 6) team layers (ping-pong)
    tail_gemm<512, 512, true><<<32, 256, 0, stream>>>(
        teams0, team_wp, team_wp + 524288, team_b,
        team_g, team_beta, teams0, teams1);
    tail_gemm<512, 512, true><<<32, 256, 0, stream>>>(
        teams1, team_wp + 262144, team_wp + 524288 + 262144, team_b + 512,
        team_g + 512, team_beta + 512, teams1, teams0);

    // 7) fused pre + lnf + pred
    tail_pred<<<32, 256, 0, stream>>>(
        teams0, pre_wp, pre_wp + 131072, pre_b, pre_g, pre_beta,
        lnf_g, lnf_b, pred_w, pred_b, (float*)d_out);
}